// Round 1
// baseline (2119.894 us; speedup 1.0000x reference)
//
#include <hip/hip_runtime.h>
#include <cstdint>
#include <cstddef>

#define NLV 5
#define NIMG 4
#define NSEL 4507          // 1000+1000+1000+1000+507 selected per image
#define TSEL (NIMG * NSEL)
#define CH 71              // ceil(4507/64)
#define PAD (CH * 64)      // 4544
#define POSTN 1000
#define TIECAP 2048
#define SDEPTH 8

__device__ const int d_W[NLV]    = {200, 100, 50, 25, 13};
__device__ const int d_NL[NLV]   = {120000, 30000, 7500, 1875, 507};
__device__ const int d_KOFF[6]   = {0, 120000, 150000, 157500, 159375, 159882};
__device__ const int d_LOFF[6]   = {0, 1000, 2000, 3000, 4000, 4507};
__device__ const int d_KL[NLV]   = {1000, 1000, 1000, 1000, 507};

struct Ptrs {
    const float* obj[NLV];
    const float* del[NLV];
    const float* anch;
};

// order-preserving map: dk ascending <=> float descending
__device__ inline unsigned int dkey_of(float f) {
    unsigned int u = __float_as_uint(f);
    unsigned int mk = (u & 0x80000000u) ? ~u : (u | 0x80000000u);
    return ~mk;
}
__device__ inline float logit_from_dkey(unsigned int dk) {
    unsigned int mk = ~dk;
    unsigned int u = (mk & 0x80000000u) ? (mk & 0x7fffffffu) : ~mk;
    return __uint_as_float(u);
}

// ---------------- per-(image,level) exact top-k selection -------------------
__global__ __launch_bounds__(1024) void k_select(Ptrs P, int* cg, float* cl) {
    __shared__ unsigned int hist[2048];
    __shared__ unsigned int cum[2048];
    __shared__ int tiebuf[TIECAP];
    __shared__ unsigned int s_bin, s_before;
    __shared__ int s_selc, s_tiec;

    int bx = blockIdx.x;
    int n = bx / NLV, l = bx % NLV;
    int tid = threadIdx.x;
    int Wl = d_W[l];
    int HW = Wl * Wl;
    int nl = d_NL[l];
    int kl = d_KL[l];
    const float* ob = P.obj[l] + (size_t)n * nl;
    int cbase = n * NSEL + d_LOFF[l];
    int koff = d_KOFF[l];

    if (kl >= nl) {  // level 4: take everything, deterministic slots
        for (int t = tid; t < nl; t += 1024) {
            int a = t / HW, rem = t - a * HW;
            int p = rem * 3 + a;
            cg[cbase + p] = koff + p;
            cl[cbase + p] = ob[t];
        }
        return;
    }

    unsigned int target = (unsigned int)kl;
    unsigned int b0, b1, b2, cnt_lt;

    auto scanfind = [&](unsigned int tgt) {
        int e0 = tid, e1 = tid + 1024;
        cum[e0] = hist[e0]; cum[e1] = hist[e1];
        __syncthreads();
        for (int d = 1; d < 2048; d <<= 1) {
            unsigned int v0 = (e0 >= d) ? cum[e0 - d] : 0u;
            unsigned int v1 = (e1 >= d) ? cum[e1 - d] : 0u;
            __syncthreads();
            cum[e0] += v0; cum[e1] += v1;
            __syncthreads();
        }
        for (int e = tid; e < 2048; e += 1024) {
            unsigned int inc = cum[e], exc = inc - hist[e];
            if (exc < tgt && tgt <= inc) { s_bin = (unsigned int)e; s_before = exc; }
        }
        __syncthreads();
    };

    // pass 1: bits [31:21]
    hist[tid] = 0; hist[tid + 1024] = 0; __syncthreads();
    for (int t = tid; t < nl; t += 1024)
        atomicAdd(&hist[dkey_of(ob[t]) >> 21], 1u);
    __syncthreads();
    scanfind(target);
    b0 = s_bin; cnt_lt = s_before;
    unsigned int t2 = target - s_before;
    __syncthreads();

    // pass 2: bits [20:10]
    hist[tid] = 0; hist[tid + 1024] = 0; __syncthreads();
    for (int t = tid; t < nl; t += 1024) {
        unsigned int dk = dkey_of(ob[t]);
        if ((dk >> 21) == b0) atomicAdd(&hist[(dk >> 10) & 0x7ffu], 1u);
    }
    __syncthreads();
    scanfind(t2);
    b1 = s_bin; cnt_lt += s_before;
    unsigned int t3 = t2 - s_before;
    __syncthreads();

    // pass 3: bits [9:0]
    hist[tid] = 0; hist[tid + 1024] = 0; __syncthreads();
    unsigned int pre22 = (b0 << 11) | b1;
    for (int t = tid; t < nl; t += 1024) {
        unsigned int dk = dkey_of(ob[t]);
        if ((dk >> 10) == pre22) atomicAdd(&hist[dk & 0x3ffu], 1u);
    }
    __syncthreads();
    scanfind(t3);
    b2 = s_bin; cnt_lt += s_before;
    unsigned int D = (b0 << 21) | (b1 << 10) | b2;
    int need = (int)(target - cnt_lt);

    // pass 4: selection + tie collection
    if (tid == 0) { s_selc = 0; s_tiec = 0; }
    __syncthreads();
    for (int t = tid; t < nl; t += 1024) {
        float lg = ob[t];
        unsigned int dk = dkey_of(lg);
        if (dk < D) {
            int pos = atomicAdd(&s_selc, 1);
            int a = t / HW, rem = t - a * HW;
            int p = rem * 3 + a;
            cg[cbase + pos] = koff + p;
            cl[cbase + pos] = lg;
        } else if (dk == D) {
            int tp = atomicAdd(&s_tiec, 1);
            if (tp < TIECAP) {
                int a = t / HW, rem = t - a * HW;
                tiebuf[tp] = rem * 3 + a;
            }
        }
    }
    __syncthreads();
    // pass 5: boundary ties, lowest indices first (top_k tie rule)
    int nt = min(s_tiec, TIECAP);
    float tlg = logit_from_dkey(D);
    for (int ti = tid; ti < nt; ti += 1024) {
        int myp = tiebuf[ti];
        int rank = 0;
        for (int j2 = 0; j2 < nt; ++j2) rank += (tiebuf[j2] < myp) ? 1 : 0;
        if (rank < need) {
            int pos = atomicAdd(&s_selc, 1);
            cg[cbase + pos] = koff + myp;
            cl[cbase + pos] = tlg;
        }
    }
}

// --------------- decode, clip, validity, sort key ---------------------------
__global__ __launch_bounds__(256) void k_build(Ptrs P, const int* cg, const float* cl,
                                               unsigned long long* keys,
                                               float4* recbox, float4* recbn) {
#pragma clang fp contract(off)
    int s = blockIdx.x * blockDim.x + threadIdx.x;
    if (s >= TSEL) return;
    int n = s / NSEL, r = s - n * NSEL;
    int gidx = cg[s];
    float lg = cl[s];
    int l = 0;
    while (l < 4 && gidx >= d_KOFF[l + 1]) ++l;
    int p = gidx - d_KOFF[l];
    int Wl = d_W[l];
    int HW = Wl * Wl;
    int a = p % 3, hw = p / 3;
    int h = hw / Wl, w = hw - h * Wl;
    const float* dl = P.del[l];
    size_t base = (size_t)(n * 12 + a * 4) * HW + (size_t)h * Wl + w;
    float dx = dl[base], dy = dl[base + HW];
    float dw = dl[base + 2 * (size_t)HW], dh = dl[base + 3 * (size_t)HW];
    const float* an = P.anch + 4 * (size_t)gidx;
    float ax1 = an[0], ay1 = an[1], ax2 = an[2], ay2 = an[3];
    float wa = ax2 - ax1, ha = ay2 - ay1;
    float cxa = ax1 + 0.5f * wa, cya = ay1 + 0.5f * ha;
    const float CLIPC = (float)4.135166556742356;
    dw = fminf(dw, CLIPC); dh = fminf(dh, CLIPC);
    float cx = dx * wa + cxa;
    float cy = dy * ha + cya;
    float ww = expf(dw) * wa;
    float hh = expf(dh) * ha;
    float x1 = cx - 0.5f * ww, y1 = cy - 0.5f * hh;
    float x2 = cx + 0.5f * ww, y2 = cy + 0.5f * hh;
    x1 = fminf(fmaxf(x1, 0.0f), 800.0f);
    y1 = fminf(fmaxf(y1, 0.0f), 800.0f);
    x2 = fminf(fmaxf(x2, 0.0f), 800.0f);
    y2 = fminf(fmaxf(y2, 0.0f), 800.0f);
    bool valid = (x2 - x1 >= 1e-3f) && (y2 - y1 >= 1e-3f);
    float off = (float)l * 801.0f;
    recbox[s] = make_float4(x1, y1, x2, y2);
    recbn[s] = make_float4(x1 + off, y1 + off, x2 + off, y2 + off);
    unsigned int sk = valid ? dkey_of(lg) : 0xffffffffu;
    keys[s] = ((unsigned long long)sk << 31) |
              ((unsigned long long)(unsigned int)gidx << 13) |
              (unsigned long long)r;
}

// --------------- per-image bitonic sort (8192 in LDS) -----------------------
__global__ __launch_bounds__(1024) void k_sort(const unsigned long long* keys,
                                               const float4* recbox, const float4* recbn,
                                               const float* cl,
                                               float4* sbox, float4* sbn, float* slog,
                                               unsigned long long* validmask) {
    __shared__ unsigned long long s[8192];
    int n = blockIdx.x, tid = threadIdx.x;
    for (int e = tid; e < 8192; e += 1024)
        s[e] = (e < NSEL) ? keys[n * NSEL + e] : 0xffffffffffffffffull;
    __syncthreads();
    for (int k = 2; k <= 8192; k <<= 1) {
        for (int j = k >> 1; j > 0; j >>= 1) {
            for (int pp = tid; pp < 4096; pp += 1024) {
                int i = ((pp & ~(j - 1)) << 1) | (pp & (j - 1));
                int ix = i | j;
                bool up = ((i & k) == 0);
                unsigned long long A = s[i], B = s[ix];
                if ((A > B) == up) { s[i] = B; s[ix] = A; }
            }
            __syncthreads();
        }
    }
    for (int r = tid; r < PAD; r += 1024) {
        if (r < NSEL) {
            unsigned long long key = s[r];
            int pos = (int)(key & 0x1fffull);
            int src = n * NSEL + pos;
            sbox[n * PAD + r] = recbox[src];
            sbn[n * PAD + r] = recbn[src];
            slog[n * PAD + r] = cl[src];
            if ((unsigned int)(key >> 31) != 0xffffffffu)
                atomicOr(&validmask[n * CH + (r >> 6)], 1ull << (r & 63));
        } else {
            sbox[n * PAD + r] = make_float4(0.f, 0.f, 0.f, 0.f);
            sbn[n * PAD + r] = make_float4(0.f, 0.f, 0.f, 0.f);
            slog[n * PAD + r] = 0.f;
        }
    }
}

// --------------- suppression bitmask: 64x64 chunk pairs ---------------------
__global__ __launch_bounds__(256) void k_mask(const float4* sbn, unsigned long long* mask) {
#pragma clang fp contract(off)
    int n = blockIdx.y;
    int ci = blockIdx.x / CH, cj = blockIdx.x - ci * CH;
    __shared__ float4 bi[64], bj[64];
    int tid = threadIdx.x;
    if (tid < 64) bj[tid] = sbn[n * PAD + cj * 64 + tid];
    else if (tid < 128) bi[tid - 64] = sbn[n * PAD + ci * 64 + (tid - 64)];
    __syncthreads();
    int wv = tid >> 6, lane = tid & 63;
    float4 B = bj[lane];
    float a2 = (B.z - B.x) * (B.w - B.y);
    for (int t = 0; t < 16; ++t) {
        int ii = wv * 16 + t;
        float4 A = bi[ii];
        float a1 = (A.z - A.x) * (A.w - A.y);
        float ltx = fmaxf(A.x, B.x), lty = fmaxf(A.y, B.y);
        float rbx = fminf(A.z, B.z), rby = fminf(A.w, B.w);
        float wx = fmaxf(rbx - ltx, 0.f), wy = fmaxf(rby - lty, 0.f);
        float inter = wx * wy;
        float iou = inter / ((a1 + a2) - inter);   // NaN for 0/0 -> compares false, like jnp
        unsigned long long word = __ballot(iou > 0.7f);
        if (lane == 0) mask[((size_t)n * PAD + (ci * 64 + ii)) * CH + cj] = word;
    }
}

// --------------- sequential greedy scan: one wave per image -----------------
__global__ __launch_bounds__(64) void k_scan(const unsigned long long* mask,
                                             const unsigned long long* validmask,
                                             unsigned long long* keepmask) {
    int n = blockIdx.x, lane = threadIdx.x;
    const unsigned long long* M = mask + (size_t)n * PAD * CH;
    unsigned long long vm0 = validmask[n * CH + lane];
    unsigned long long vm1 = (lane < CH - 64) ? validmask[n * CH + 64 + lane] : 0ull;
    unsigned long long r0 = 0, r1 = 0, k0 = 0, k1 = 0;
    unsigned long long buf[2][SDEPTH][2];

    auto ld = [&](int cb, int b) {
#pragma unroll
        for (int t = 0; t < SDEPTH; ++t) {
            size_t row = (size_t)(cb + t) * CH;
            buf[b][t][0] = M[row + lane];
            buf[b][t][1] = (lane < CH - 64) ? M[row + 64 + lane] : 0ull;
        }
    };
    const int nch = (NSEL + SDEPTH - 1) / SDEPTH;
    ld(0, 0);
    for (int c = 0; c < nch; ++c) {
        if (c + 1 < nch) ld((c + 1) * SDEPTH, (c + 1) & 1);
#pragma unroll
        for (int t = 0; t < SDEPTH; ++t) {
            int i = c * SDEPTH + t;
            if (i >= NSEL) break;
            int q = i >> 6, bit = i & 63;
            unsigned long long rw = (q < 64) ? __shfl(r0, q) : __shfl(r1, q - 64);
            unsigned long long vw = (q < 64) ? __shfl(vm0, q) : __shfl(vm1, q - 64);
            if (((vw >> bit) & 1ull) && !((rw >> bit) & 1ull)) {
                r0 |= buf[c & 1][t][0];
                r1 |= buf[c & 1][t][1];
                unsigned long long bb = 1ull << bit;
                if (q < 64) { if (lane == q) k0 |= bb; }
                else if (lane == q - 64) k1 |= bb;
            }
        }
    }
    keepmask[n * CH + lane] = k0;
    if (lane < CH - 64) keepmask[n * CH + 64 + lane] = k1;
}

// --------------- emit first 1000 kept (score order) -------------------------
__global__ __launch_bounds__(256) void k_epi(const unsigned long long* keepmask,
                                             const float4* sbox, const float* slog,
                                             float* out) {
    int n = blockIdx.x, tid = threadIdx.x;
    __shared__ unsigned long long kw[CH];
    __shared__ int pref[CH];
    if (tid < CH) kw[tid] = keepmask[n * CH + tid];
    __syncthreads();
    if (tid == 0) {
        int run = 0;
        for (int w2 = 0; w2 < CH; ++w2) { pref[w2] = run; run += __popcll(kw[w2]); }
    }
    __syncthreads();
    for (int i = tid; i < NSEL; i += 256) {
        int q = i >> 6, b = i & 63;
        if ((kw[q] >> b) & 1ull) {
            int rank = pref[q] + __popcll(kw[q] & ((1ull << b) - 1ull));
            if (rank < POSTN) {
                float4 bx = sbox[n * PAD + i];
                float lg = slog[n * PAD + i];
                ((float4*)out)[n * POSTN + rank] = bx;
                out[NIMG * POSTN * 4 + n * POSTN + rank] = 1.0f / (1.0f + expf(-lg));
            }
        }
    }
}

extern "C" void kernel_launch(void* const* d_in, const int* in_sizes, int n_in,
                              void* d_out, int out_size, void* d_ws, size_t ws_size,
                              hipStream_t stream) {
    Ptrs P;
    bool interleaved = (in_sizes[1] == 4 * in_sizes[0]);  // obj0,delta0,obj1,... vs obj0..4,delta0..4
    for (int i = 0; i < NLV; ++i) {
        if (interleaved) {
            P.obj[i] = (const float*)d_in[2 * i];
            P.del[i] = (const float*)d_in[2 * i + 1];
        } else {
            P.obj[i] = (const float*)d_in[i];
            P.del[i] = (const float*)d_in[NLV + i];
        }
    }
    P.anch = (const float*)d_in[10];

    char* w = (char*)d_ws;
    size_t off = 0;
    auto alloc = [&](size_t bytes) {
        void* p = w + off;
        off = (off + bytes + 255) & ~(size_t)255;
        return p;
    };
    unsigned long long* validmask = (unsigned long long*)alloc((size_t)NIMG * CH * 8);
    unsigned long long* keepmask  = (unsigned long long*)alloc((size_t)NIMG * CH * 8);
    int* cg      = (int*)alloc((size_t)TSEL * 4);
    float* cl    = (float*)alloc((size_t)TSEL * 4);
    unsigned long long* keys = (unsigned long long*)alloc((size_t)TSEL * 8);
    float4* recbox = (float4*)alloc((size_t)TSEL * 16);
    float4* recbn  = (float4*)alloc((size_t)TSEL * 16);
    float4* sbox = (float4*)alloc((size_t)NIMG * PAD * 16);
    float4* sbn  = (float4*)alloc((size_t)NIMG * PAD * 16);
    float* slog  = (float*)alloc((size_t)NIMG * PAD * 4);
    unsigned long long* mask = (unsigned long long*)alloc((size_t)NIMG * PAD * CH * 8);
    (void)ws_size; (void)n_in;

    (void)hipMemsetAsync(d_out, 0, (size_t)out_size * 4, stream);
    (void)hipMemsetAsync(validmask, 0, (size_t)NIMG * CH * 8, stream);

    k_select<<<NIMG * NLV, 1024, 0, stream>>>(P, cg, cl);
    k_build<<<(TSEL + 255) / 256, 256, 0, stream>>>(P, cg, cl, keys, recbox, recbn);
    k_sort<<<NIMG, 1024, 0, stream>>>(keys, recbox, recbn, cl, sbox, sbn, slog, validmask);
    k_mask<<<dim3(CH * CH, NIMG), 256, 0, stream>>>(sbn, mask);
    k_scan<<<NIMG, 64, 0, stream>>>(mask, validmask, keepmask);
    k_epi<<<NIMG, 256, 0, stream>>>(keepmask, sbox, slog, (float*)d_out);
}

// Round 2
// 926.640 us; speedup vs baseline: 2.2877x; 2.2877x over previous
//
#include <hip/hip_runtime.h>
#include <cstdint>
#include <cstddef>

#define NLV 5
#define NIMG 4
#define NSEL 4507          // 1000+1000+1000+1000+507 selected per image
#define TSEL (NIMG * NSEL)
#define CH 71              // ceil(4507/64)
#define PAD (CH * 64)      // 4544
#define POSTN 1000
#define TIECAP 2048

__device__ const int d_W[NLV]    = {200, 100, 50, 25, 13};
__device__ const int d_NL[NLV]   = {120000, 30000, 7500, 1875, 507};
__device__ const int d_KOFF[6]   = {0, 120000, 150000, 157500, 159375, 159882};
__device__ const int d_LOFF[6]   = {0, 1000, 2000, 3000, 4000, 4507};
__device__ const int d_KL[NLV]   = {1000, 1000, 1000, 1000, 507};

struct Ptrs {
    const float* obj[NLV];
    const float* del[NLV];
    const float* anch;
};

// order-preserving map: dk ascending <=> float descending
__device__ inline unsigned int dkey_of(float f) {
    unsigned int u = __float_as_uint(f);
    unsigned int mk = (u & 0x80000000u) ? ~u : (u | 0x80000000u);
    return ~mk;
}
__device__ inline float logit_from_dkey(unsigned int dk) {
    unsigned int mk = ~dk;
    unsigned int u = (mk & 0x80000000u) ? (mk & 0x7fffffffu) : ~mk;
    return __uint_as_float(u);
}

// ---------------- per-(image,level) exact top-k selection -------------------
__global__ __launch_bounds__(1024) void k_select(Ptrs P, int* cg, float* cl) {
    __shared__ unsigned int hist[2048];
    __shared__ unsigned int cum[2048];
    __shared__ int tiebuf[TIECAP];
    __shared__ unsigned int s_bin, s_before;
    __shared__ int s_selc, s_tiec;

    int bx = blockIdx.x;
    int n = bx / NLV, l = bx % NLV;
    int tid = threadIdx.x;
    int Wl = d_W[l];
    int HW = Wl * Wl;
    int nl = d_NL[l];
    int kl = d_KL[l];
    const float* ob = P.obj[l] + (size_t)n * nl;
    int cbase = n * NSEL + d_LOFF[l];
    int koff = d_KOFF[l];

    if (kl >= nl) {  // level 4: take everything, deterministic slots
        for (int t = tid; t < nl; t += 1024) {
            int a = t / HW, rem = t - a * HW;
            int p = rem * 3 + a;
            cg[cbase + p] = koff + p;
            cl[cbase + p] = ob[t];
        }
        return;
    }

    unsigned int target = (unsigned int)kl;
    unsigned int b0, b1, b2, cnt_lt;

    auto scanfind = [&](unsigned int tgt) {
        int e0 = tid, e1 = tid + 1024;
        cum[e0] = hist[e0]; cum[e1] = hist[e1];
        __syncthreads();
        for (int d = 1; d < 2048; d <<= 1) {
            unsigned int v0 = (e0 >= d) ? cum[e0 - d] : 0u;
            unsigned int v1 = (e1 >= d) ? cum[e1 - d] : 0u;
            __syncthreads();
            cum[e0] += v0; cum[e1] += v1;
            __syncthreads();
        }
        for (int e = tid; e < 2048; e += 1024) {
            unsigned int inc = cum[e], exc = inc - hist[e];
            if (exc < tgt && tgt <= inc) { s_bin = (unsigned int)e; s_before = exc; }
        }
        __syncthreads();
    };

    // pass 1: bits [31:21]
    hist[tid] = 0; hist[tid + 1024] = 0; __syncthreads();
    for (int t = tid; t < nl; t += 1024)
        atomicAdd(&hist[dkey_of(ob[t]) >> 21], 1u);
    __syncthreads();
    scanfind(target);
    b0 = s_bin; cnt_lt = s_before;
    unsigned int t2 = target - s_before;
    __syncthreads();

    // pass 2: bits [20:10]
    hist[tid] = 0; hist[tid + 1024] = 0; __syncthreads();
    for (int t = tid; t < nl; t += 1024) {
        unsigned int dk = dkey_of(ob[t]);
        if ((dk >> 21) == b0) atomicAdd(&hist[(dk >> 10) & 0x7ffu], 1u);
    }
    __syncthreads();
    scanfind(t2);
    b1 = s_bin; cnt_lt += s_before;
    unsigned int t3 = t2 - s_before;
    __syncthreads();

    // pass 3: bits [9:0]
    hist[tid] = 0; hist[tid + 1024] = 0; __syncthreads();
    unsigned int pre22 = (b0 << 11) | b1;
    for (int t = tid; t < nl; t += 1024) {
        unsigned int dk = dkey_of(ob[t]);
        if ((dk >> 10) == pre22) atomicAdd(&hist[dk & 0x3ffu], 1u);
    }
    __syncthreads();
    scanfind(t3);
    b2 = s_bin; cnt_lt += s_before;
    unsigned int D = (b0 << 21) | (b1 << 10) | b2;
    int need = (int)(target - cnt_lt);

    // pass 4: selection + tie collection
    if (tid == 0) { s_selc = 0; s_tiec = 0; }
    __syncthreads();
    for (int t = tid; t < nl; t += 1024) {
        float lg = ob[t];
        unsigned int dk = dkey_of(lg);
        if (dk < D) {
            int pos = atomicAdd(&s_selc, 1);
            int a = t / HW, rem = t - a * HW;
            int p = rem * 3 + a;
            cg[cbase + pos] = koff + p;
            cl[cbase + pos] = lg;
        } else if (dk == D) {
            int tp = atomicAdd(&s_tiec, 1);
            if (tp < TIECAP) {
                int a = t / HW, rem = t - a * HW;
                tiebuf[tp] = rem * 3 + a;
            }
        }
    }
    __syncthreads();
    // pass 5: boundary ties, lowest indices first (top_k tie rule)
    int nt = min(s_tiec, TIECAP);
    float tlg = logit_from_dkey(D);
    for (int ti = tid; ti < nt; ti += 1024) {
        int myp = tiebuf[ti];
        int rank = 0;
        for (int j2 = 0; j2 < nt; ++j2) rank += (tiebuf[j2] < myp) ? 1 : 0;
        if (rank < need) {
            int pos = atomicAdd(&s_selc, 1);
            cg[cbase + pos] = koff + myp;
            cl[cbase + pos] = tlg;
        }
    }
}

// --------------- decode, clip, validity, sort key ---------------------------
__global__ __launch_bounds__(256) void k_build(Ptrs P, const int* cg, const float* cl,
                                               unsigned long long* keys,
                                               float4* recbox, float4* recbn) {
#pragma clang fp contract(off)
    int s = blockIdx.x * blockDim.x + threadIdx.x;
    if (s >= TSEL) return;
    int n = s / NSEL, r = s - n * NSEL;
    int gidx = cg[s];
    float lg = cl[s];
    int l = 0;
    while (l < 4 && gidx >= d_KOFF[l + 1]) ++l;
    int p = gidx - d_KOFF[l];
    int Wl = d_W[l];
    int HW = Wl * Wl;
    int a = p % 3, hw = p / 3;
    int h = hw / Wl, w = hw - h * Wl;
    const float* dl = P.del[l];
    size_t base = (size_t)(n * 12 + a * 4) * HW + (size_t)h * Wl + w;
    float dx = dl[base], dy = dl[base + HW];
    float dw = dl[base + 2 * (size_t)HW], dh = dl[base + 3 * (size_t)HW];
    const float* an = P.anch + 4 * (size_t)gidx;
    float ax1 = an[0], ay1 = an[1], ax2 = an[2], ay2 = an[3];
    float wa = ax2 - ax1, ha = ay2 - ay1;
    float cxa = ax1 + 0.5f * wa, cya = ay1 + 0.5f * ha;
    const float CLIPC = (float)4.135166556742356;
    dw = fminf(dw, CLIPC); dh = fminf(dh, CLIPC);
    float cx = dx * wa + cxa;
    float cy = dy * ha + cya;
    float ww = expf(dw) * wa;
    float hh = expf(dh) * ha;
    float x1 = cx - 0.5f * ww, y1 = cy - 0.5f * hh;
    float x2 = cx + 0.5f * ww, y2 = cy + 0.5f * hh;
    x1 = fminf(fmaxf(x1, 0.0f), 800.0f);
    y1 = fminf(fmaxf(y1, 0.0f), 800.0f);
    x2 = fminf(fmaxf(x2, 0.0f), 800.0f);
    y2 = fminf(fmaxf(y2, 0.0f), 800.0f);
    bool valid = (x2 - x1 >= 1e-3f) && (y2 - y1 >= 1e-3f);
    float off = (float)l * 801.0f;
    recbox[s] = make_float4(x1, y1, x2, y2);
    recbn[s] = make_float4(x1 + off, y1 + off, x2 + off, y2 + off);
    unsigned int sk = valid ? dkey_of(lg) : 0xffffffffu;
    keys[s] = ((unsigned long long)sk << 31) |
              ((unsigned long long)(unsigned int)gidx << 13) |
              (unsigned long long)r;
}

// --------------- per-image bitonic sort (8192 in LDS) -----------------------
__global__ __launch_bounds__(1024) void k_sort(const unsigned long long* keys,
                                               const float4* recbox, const float4* recbn,
                                               const float* cl,
                                               float4* sbox, float4* sbn, float* slog,
                                               unsigned long long* validmask) {
    __shared__ unsigned long long s[8192];
    int n = blockIdx.x, tid = threadIdx.x;
    for (int e = tid; e < 8192; e += 1024)
        s[e] = (e < NSEL) ? keys[n * NSEL + e] : 0xffffffffffffffffull;
    __syncthreads();
    for (int k = 2; k <= 8192; k <<= 1) {
        for (int j = k >> 1; j > 0; j >>= 1) {
            for (int pp = tid; pp < 4096; pp += 1024) {
                int i = ((pp & ~(j - 1)) << 1) | (pp & (j - 1));
                int ix = i | j;
                bool up = ((i & k) == 0);
                unsigned long long A = s[i], B = s[ix];
                if ((A > B) == up) { s[i] = B; s[ix] = A; }
            }
            __syncthreads();
        }
    }
    for (int r = tid; r < PAD; r += 1024) {
        if (r < NSEL) {
            unsigned long long key = s[r];
            int pos = (int)(key & 0x1fffull);
            int src = n * NSEL + pos;
            sbox[n * PAD + r] = recbox[src];
            sbn[n * PAD + r] = recbn[src];
            slog[n * PAD + r] = cl[src];
            if ((unsigned int)(key >> 31) != 0xffffffffu)
                atomicOr(&validmask[n * CH + (r >> 6)], 1ull << (r & 63));
        } else {
            sbox[n * PAD + r] = make_float4(0.f, 0.f, 0.f, 0.f);
            sbn[n * PAD + r] = make_float4(0.f, 0.f, 0.f, 0.f);
            slog[n * PAD + r] = 0.f;
        }
    }
}

// --------------- suppression bitmask: upper-triangular chunk pairs ----------
__global__ __launch_bounds__(256) void k_mask(const float4* sbn, unsigned long long* mask) {
#pragma clang fp contract(off)
    int cj = blockIdx.x, ci = blockIdx.y, n = blockIdx.z;
    if (cj < ci) return;   // scan only reads column-words >= row's chunk
    __shared__ float4 bi[64], bj[64];
    int tid = threadIdx.x;
    if (tid < 64) bj[tid] = sbn[n * PAD + cj * 64 + tid];
    else if (tid < 128) bi[tid - 64] = sbn[n * PAD + ci * 64 + (tid - 64)];
    __syncthreads();
    int wv = tid >> 6, lane = tid & 63;
    float4 B = bj[lane];
    float a2 = (B.z - B.x) * (B.w - B.y);
    for (int t = 0; t < 16; ++t) {
        int ii = wv * 16 + t;
        float4 A = bi[ii];
        float a1 = (A.z - A.x) * (A.w - A.y);
        float ltx = fmaxf(A.x, B.x), lty = fmaxf(A.y, B.y);
        float rbx = fminf(A.z, B.z), rby = fminf(A.w, B.w);
        float wx = fmaxf(rbx - ltx, 0.f), wy = fmaxf(rby - lty, 0.f);
        float inter = wx * wy;
        float iou = inter / ((a1 + a2) - inter);   // NaN for 0/0 -> compares false, like jnp
        unsigned long long word = __ballot(iou > 0.7f);
        if (lane == 0) mask[((size_t)n * PAD + (ci * 64 + ii)) * CH + cj] = word;
    }
}

// --------------- chunked greedy scan: 4 waves per image ---------------------
// Intra-chunk: wave 0 resolves 64 boxes in registers (pend/ffs loop, one
// iteration per KEPT box, shfl broadcasts the suppression row word).
// Inter-chunk: all 4 waves OR kept rows into the removed vector for later
// column-words (coalesced row reads, 4-batched => 16 loads in flight).
__global__ __launch_bounds__(256) void k_scan2(const unsigned long long* mask,
                                               const unsigned long long* validmask,
                                               unsigned long long* keepmask) {
    int n = blockIdx.x;
    int tid = threadIdx.x;
    int w = tid >> 6, lane = tid & 63;
    const unsigned long long* M = mask + (size_t)n * PAD * CH;
    __shared__ unsigned long long R[CH];          // removed, per column-word
    __shared__ unsigned long long Rpart[4][CH];   // per-wave partial ORs
    __shared__ unsigned long long s_keep[CH];
    __shared__ int list[64];
    __shared__ int s_kc;

    for (int j = tid; j < CH; j += 256) { R[j] = 0; s_keep[j] = 0; }
    __syncthreads();

    for (int c = 0; c < CH; ++c) {
        // zero partials (columns <= c stay 0 and are never merged)
        for (int j = tid; j < 4 * CH; j += 256) ((unsigned long long*)Rpart)[j] = 0;

        if (w == 0) {
            // diagonal 64x64 block: lane holds its row's column-word c
            unsigned long long D = M[(size_t)(c * 64 + lane) * CH + c];
            unsigned long long Rc = R[c];
            unsigned long long Vc = validmask[n * CH + c];
            unsigned long long Kc = 0;
            unsigned long long pend = Vc & ~Rc;   // candidates (valid bits already < NSEL)
            int kc = 0;
            while (pend) {
                int b = __ffsll((long long)pend) - 1;
                Kc |= 1ull << b;
                if (lane == 0) list[kc] = c * 64 + b;
                ++kc;
                unsigned long long row_b = __shfl(D, b);
                Rc |= row_b;                       // self-bit included (iou=1), harmless
                pend &= ~Rc;
            }
            if (lane == 0) { s_kc = kc; s_keep[c] = Kc; R[c] = Rc; }
        }
        __syncthreads();

        int kc = s_kc;
        int j0 = c + 1 + lane;        // this lane's column-words
        int j1 = c + 65 + lane;
        unsigned long long a0 = 0, a1 = 0;
        int e = w;
        for (; e + 12 < kc; e += 16) {             // wave handles e, e+4, e+8, e+12
            const unsigned long long* p0 = M + (size_t)list[e] * CH;
            const unsigned long long* p1 = M + (size_t)list[e + 4] * CH;
            const unsigned long long* p2 = M + (size_t)list[e + 8] * CH;
            const unsigned long long* p3 = M + (size_t)list[e + 12] * CH;
            if (j0 < CH) { a0 |= p0[j0] | p1[j0] | p2[j0] | p3[j0]; }
            if (j1 < CH) { a1 |= p0[j1] | p1[j1] | p2[j1] | p3[j1]; }
        }
        for (; e < kc; e += 4) {
            const unsigned long long* p0 = M + (size_t)list[e] * CH;
            if (j0 < CH) a0 |= p0[j0];
            if (j1 < CH) a1 |= p0[j1];
        }
        if (j0 < CH) Rpart[w][j0] = a0;
        if (j1 < CH) Rpart[w][j1] = a1;
        __syncthreads();
        for (int j = c + 1 + tid; j < CH; j += 256)
            R[j] |= Rpart[0][j] | Rpart[1][j] | Rpart[2][j] | Rpart[3][j];
        __syncthreads();
    }
    for (int j = tid; j < CH; j += 256) keepmask[n * CH + j] = s_keep[j];
}

// --------------- emit first 1000 kept (score order) -------------------------
__global__ __launch_bounds__(256) void k_epi(const unsigned long long* keepmask,
                                             const float4* sbox, const float* slog,
                                             float* out) {
    int n = blockIdx.x, tid = threadIdx.x;
    __shared__ unsigned long long kw[CH];
    __shared__ int pref[CH];
    if (tid < CH) kw[tid] = keepmask[n * CH + tid];
    __syncthreads();
    if (tid == 0) {
        int run = 0;
        for (int w2 = 0; w2 < CH; ++w2) { pref[w2] = run; run += __popcll(kw[w2]); }
    }
    __syncthreads();
    for (int i = tid; i < NSEL; i += 256) {
        int q = i >> 6, b = i & 63;
        if ((kw[q] >> b) & 1ull) {
            int rank = pref[q] + __popcll(kw[q] & ((1ull << b) - 1ull));
            if (rank < POSTN) {
                float4 bx = sbox[n * PAD + i];
                float lg = slog[n * PAD + i];
                ((float4*)out)[n * POSTN + rank] = bx;
                out[NIMG * POSTN * 4 + n * POSTN + rank] = 1.0f / (1.0f + expf(-lg));
            }
        }
    }
}

extern "C" void kernel_launch(void* const* d_in, const int* in_sizes, int n_in,
                              void* d_out, int out_size, void* d_ws, size_t ws_size,
                              hipStream_t stream) {
    Ptrs P;
    bool interleaved = (in_sizes[1] == 4 * in_sizes[0]);  // obj0,delta0,obj1,... vs obj0..4,delta0..4
    for (int i = 0; i < NLV; ++i) {
        if (interleaved) {
            P.obj[i] = (const float*)d_in[2 * i];
            P.del[i] = (const float*)d_in[2 * i + 1];
        } else {
            P.obj[i] = (const float*)d_in[i];
            P.del[i] = (const float*)d_in[NLV + i];
        }
    }
    P.anch = (const float*)d_in[10];

    char* w = (char*)d_ws;
    size_t off = 0;
    auto alloc = [&](size_t bytes) {
        void* p = w + off;
        off = (off + bytes + 255) & ~(size_t)255;
        return p;
    };
    unsigned long long* validmask = (unsigned long long*)alloc((size_t)NIMG * CH * 8);
    unsigned long long* keepmask  = (unsigned long long*)alloc((size_t)NIMG * CH * 8);
    int* cg      = (int*)alloc((size_t)TSEL * 4);
    float* cl    = (float*)alloc((size_t)TSEL * 4);
    unsigned long long* keys = (unsigned long long*)alloc((size_t)TSEL * 8);
    float4* recbox = (float4*)alloc((size_t)TSEL * 16);
    float4* recbn  = (float4*)alloc((size_t)TSEL * 16);
    float4* sbox = (float4*)alloc((size_t)NIMG * PAD * 16);
    float4* sbn  = (float4*)alloc((size_t)NIMG * PAD * 16);
    float* slog  = (float*)alloc((size_t)NIMG * PAD * 4);
    unsigned long long* mask = (unsigned long long*)alloc((size_t)NIMG * PAD * CH * 8);
    (void)ws_size; (void)n_in;

    (void)hipMemsetAsync(d_out, 0, (size_t)out_size * 4, stream);
    (void)hipMemsetAsync(validmask, 0, (size_t)NIMG * CH * 8, stream);

    k_select<<<NIMG * NLV, 1024, 0, stream>>>(P, cg, cl);
    k_build<<<(TSEL + 255) / 256, 256, 0, stream>>>(P, cg, cl, keys, recbox, recbn);
    k_sort<<<NIMG, 1024, 0, stream>>>(keys, recbox, recbn, cl, sbox, sbn, slog, validmask);
    k_mask<<<dim3(CH, CH, NIMG), 256, 0, stream>>>(sbn, mask);
    k_scan2<<<NIMG, 256, 0, stream>>>(mask, validmask, keepmask);
    k_epi<<<NIMG, 256, 0, stream>>>(keepmask, sbox, slog, (float*)d_out);
}

// Round 3
// 790.864 us; speedup vs baseline: 2.6805x; 1.1717x over previous
//
#include <hip/hip_runtime.h>
#include <cstdint>
#include <cstddef>

#define NLV 5
#define NIMG 4
#define NSEL 4507          // 1000+1000+1000+1000+507 selected per image
#define TSEL (NIMG * NSEL)
#define CH 71              // ceil(4507/64)
#define PAD (CH * 64)      // 4544
#define POSTN 1000
#define TIECAP 2048

__device__ const int d_W[NLV]    = {200, 100, 50, 25, 13};
__device__ const int d_NL[NLV]   = {120000, 30000, 7500, 1875, 507};
__device__ const int d_KOFF[6]   = {0, 120000, 150000, 157500, 159375, 159882};
__device__ const int d_LOFF[6]   = {0, 1000, 2000, 3000, 4000, 4507};
__device__ const int d_KL[NLV]   = {1000, 1000, 1000, 1000, 507};

struct Ptrs {
    const float* obj[NLV];
    const float* del[NLV];
    const float* anch;
};

// order-preserving map: dk ascending <=> float descending
__device__ inline unsigned int dkey_of(float f) {
    unsigned int u = __float_as_uint(f);
    unsigned int mk = (u & 0x80000000u) ? ~u : (u | 0x80000000u);
    return ~mk;
}
__device__ inline float logit_from_dkey(unsigned int dk) {
    unsigned int mk = ~dk;
    unsigned int u = (mk & 0x80000000u) ? (mk & 0x7fffffffu) : ~mk;
    return __uint_as_float(u);
}

// ---------------- per-(image,level) exact top-k selection -------------------
__global__ __launch_bounds__(1024) void k_select(Ptrs P, int* cg, float* cl) {
    __shared__ unsigned int hist[2048];
    __shared__ unsigned int cum[2048];
    __shared__ int tiebuf[TIECAP];
    __shared__ unsigned int s_bin, s_before;
    __shared__ int s_selc, s_tiec;

    int bx = blockIdx.x;
    int n = bx / NLV, l = bx % NLV;
    int tid = threadIdx.x;
    int Wl = d_W[l];
    int HW = Wl * Wl;
    int nl = d_NL[l];
    int kl = d_KL[l];
    const float* ob = P.obj[l] + (size_t)n * nl;
    int cbase = n * NSEL + d_LOFF[l];
    int koff = d_KOFF[l];

    if (kl >= nl) {  // level 4: take everything, deterministic slots
        for (int t = tid; t < nl; t += 1024) {
            int a = t / HW, rem = t - a * HW;
            int p = rem * 3 + a;
            cg[cbase + p] = koff + p;
            cl[cbase + p] = ob[t];
        }
        return;
    }

    unsigned int target = (unsigned int)kl;
    unsigned int b0, b1, b2, cnt_lt;

    auto scanfind = [&](unsigned int tgt) {
        int e0 = tid, e1 = tid + 1024;
        cum[e0] = hist[e0]; cum[e1] = hist[e1];
        __syncthreads();
        for (int d = 1; d < 2048; d <<= 1) {
            unsigned int v0 = (e0 >= d) ? cum[e0 - d] : 0u;
            unsigned int v1 = (e1 >= d) ? cum[e1 - d] : 0u;
            __syncthreads();
            cum[e0] += v0; cum[e1] += v1;
            __syncthreads();
        }
        for (int e = tid; e < 2048; e += 1024) {
            unsigned int inc = cum[e], exc = inc - hist[e];
            if (exc < tgt && tgt <= inc) { s_bin = (unsigned int)e; s_before = exc; }
        }
        __syncthreads();
    };

    // pass 1: bits [31:21]
    hist[tid] = 0; hist[tid + 1024] = 0; __syncthreads();
    for (int t = tid; t < nl; t += 1024)
        atomicAdd(&hist[dkey_of(ob[t]) >> 21], 1u);
    __syncthreads();
    scanfind(target);
    b0 = s_bin; cnt_lt = s_before;
    unsigned int t2 = target - s_before;
    __syncthreads();

    // pass 2: bits [20:10]
    hist[tid] = 0; hist[tid + 1024] = 0; __syncthreads();
    for (int t = tid; t < nl; t += 1024) {
        unsigned int dk = dkey_of(ob[t]);
        if ((dk >> 21) == b0) atomicAdd(&hist[(dk >> 10) & 0x7ffu], 1u);
    }
    __syncthreads();
    scanfind(t2);
    b1 = s_bin; cnt_lt += s_before;
    unsigned int t3 = t2 - s_before;
    __syncthreads();

    // pass 3: bits [9:0]
    hist[tid] = 0; hist[tid + 1024] = 0; __syncthreads();
    unsigned int pre22 = (b0 << 11) | b1;
    for (int t = tid; t < nl; t += 1024) {
        unsigned int dk = dkey_of(ob[t]);
        if ((dk >> 10) == pre22) atomicAdd(&hist[dk & 0x3ffu], 1u);
    }
    __syncthreads();
    scanfind(t3);
    b2 = s_bin; cnt_lt += s_before;
    unsigned int D = (b0 << 21) | (b1 << 10) | b2;
    int need = (int)(target - cnt_lt);

    // pass 4: selection + tie collection
    if (tid == 0) { s_selc = 0; s_tiec = 0; }
    __syncthreads();
    for (int t = tid; t < nl; t += 1024) {
        float lg = ob[t];
        unsigned int dk = dkey_of(lg);
        if (dk < D) {
            int pos = atomicAdd(&s_selc, 1);
            int a = t / HW, rem = t - a * HW;
            int p = rem * 3 + a;
            cg[cbase + pos] = koff + p;
            cl[cbase + pos] = lg;
        } else if (dk == D) {
            int tp = atomicAdd(&s_tiec, 1);
            if (tp < TIECAP) {
                int a = t / HW, rem = t - a * HW;
                tiebuf[tp] = rem * 3 + a;
            }
        }
    }
    __syncthreads();
    // pass 5: boundary ties, lowest indices first (top_k tie rule)
    int nt = min(s_tiec, TIECAP);
    float tlg = logit_from_dkey(D);
    for (int ti = tid; ti < nt; ti += 1024) {
        int myp = tiebuf[ti];
        int rank = 0;
        for (int j2 = 0; j2 < nt; ++j2) rank += (tiebuf[j2] < myp) ? 1 : 0;
        if (rank < need) {
            int pos = atomicAdd(&s_selc, 1);
            cg[cbase + pos] = koff + myp;
            cl[cbase + pos] = tlg;
        }
    }
}

// --------------- decode, clip, validity, sort key ---------------------------
__global__ __launch_bounds__(256) void k_build(Ptrs P, const int* cg, const float* cl,
                                               unsigned long long* keys,
                                               float4* recbox, float4* recbn) {
#pragma clang fp contract(off)
    int s = blockIdx.x * blockDim.x + threadIdx.x;
    if (s >= TSEL) return;
    int n = s / NSEL, r = s - n * NSEL;
    int gidx = cg[s];
    float lg = cl[s];
    int l = 0;
    while (l < 4 && gidx >= d_KOFF[l + 1]) ++l;
    int p = gidx - d_KOFF[l];
    int Wl = d_W[l];
    int HW = Wl * Wl;
    int a = p % 3, hw = p / 3;
    int h = hw / Wl, w = hw - h * Wl;
    const float* dl = P.del[l];
    size_t base = (size_t)(n * 12 + a * 4) * HW + (size_t)h * Wl + w;
    float dx = dl[base], dy = dl[base + HW];
    float dw = dl[base + 2 * (size_t)HW], dh = dl[base + 3 * (size_t)HW];
    const float* an = P.anch + 4 * (size_t)gidx;
    float ax1 = an[0], ay1 = an[1], ax2 = an[2], ay2 = an[3];
    float wa = ax2 - ax1, ha = ay2 - ay1;
    float cxa = ax1 + 0.5f * wa, cya = ay1 + 0.5f * ha;
    const float CLIPC = (float)4.135166556742356;
    dw = fminf(dw, CLIPC); dh = fminf(dh, CLIPC);
    float cx = dx * wa + cxa;
    float cy = dy * ha + cya;
    float ww = expf(dw) * wa;
    float hh = expf(dh) * ha;
    float x1 = cx - 0.5f * ww, y1 = cy - 0.5f * hh;
    float x2 = cx + 0.5f * ww, y2 = cy + 0.5f * hh;
    x1 = fminf(fmaxf(x1, 0.0f), 800.0f);
    y1 = fminf(fmaxf(y1, 0.0f), 800.0f);
    x2 = fminf(fmaxf(x2, 0.0f), 800.0f);
    y2 = fminf(fmaxf(y2, 0.0f), 800.0f);
    bool valid = (x2 - x1 >= 1e-3f) && (y2 - y1 >= 1e-3f);
    float off = (float)l * 801.0f;
    recbox[s] = make_float4(x1, y1, x2, y2);
    recbn[s] = make_float4(x1 + off, y1 + off, x2 + off, y2 + off);
    unsigned int sk = valid ? dkey_of(lg) : 0xffffffffu;
    keys[s] = ((unsigned long long)sk << 31) |
              ((unsigned long long)(unsigned int)gidx << 13) |
              (unsigned long long)r;
}

// --------------- per-image bitonic sort (8192 in LDS) -----------------------
__global__ __launch_bounds__(1024) void k_sort(const unsigned long long* keys,
                                               const float4* recbox, const float4* recbn,
                                               const float* cl,
                                               float4* sbox, float4* sbn, float* slog,
                                               int* sinfo) {
    __shared__ unsigned long long s[8192];
    int n = blockIdx.x, tid = threadIdx.x;
    for (int e = tid; e < 8192; e += 1024)
        s[e] = (e < NSEL) ? keys[n * NSEL + e] : 0xffffffffffffffffull;
    __syncthreads();
    for (int k = 2; k <= 8192; k <<= 1) {
        for (int j = k >> 1; j > 0; j >>= 1) {
            for (int pp = tid; pp < 4096; pp += 1024) {
                int i = ((pp & ~(j - 1)) << 1) | (pp & (j - 1));
                int ix = i | j;
                bool up = ((i & k) == 0);
                unsigned long long A = s[i], B = s[ix];
                if ((A > B) == up) { s[i] = B; s[ix] = A; }
            }
            __syncthreads();
        }
    }
    for (int r = tid; r < PAD; r += 1024) {
        if (r < NSEL) {
            unsigned long long key = s[r];
            int pos = (int)(key & 0x1fffull);
            int src = n * NSEL + pos;
            sbox[n * PAD + r] = recbox[src];
            sbn[n * PAD + r] = recbn[src];
            slog[n * PAD + r] = cl[src];
            bool valid = ((unsigned int)(key >> 31) != 0xffffffffu);
            int lvl = (pos >= 4000) ? 4 : (pos >= 3000) ? 3 : (pos >= 2000) ? 2
                      : (pos >= 1000) ? 1 : 0;
            sinfo[n * PAD + r] = valid ? lvl : -1;
        } else {
            sbox[n * PAD + r] = make_float4(0.f, 0.f, 0.f, 0.f);
            sbn[n * PAD + r] = make_float4(0.f, 0.f, 0.f, 0.f);
            slog[n * PAD + r] = 0.f;
            sinfo[n * PAD + r] = -1;
        }
    }
}

// --------------- per-(image,level) LDS-resident greedy NMS ------------------
// Cross-level IoU is exactly 0 (level*801 offsets, boxes clipped to [0,800]),
// so greedy NMS over the global sorted order decomposes exactly into 5
// independent per-level NMS problems. Each block: compact its level's valid
// boxes (sorted order preserved) into LDS, then chunked greedy NMS with
// ballot-computed 64x64 diagonal IoU and on-the-fly suppression of later
// chunks. No global memory in the chunk loop.
__global__ __launch_bounds__(256) void k_nms(const float4* sbn, const int* sinfo,
                                             unsigned long long* keepmask) {
#pragma clang fp contract(off)
    int l = blockIdx.x, n = blockIdx.y;
    int tid = threadIdx.x, w = tid >> 6, lane = tid & 63;
    __shared__ float4 lbox[1024];
    __shared__ short lrank[1024];
    __shared__ int scan[256];
    __shared__ unsigned long long Dg[64];
    __shared__ unsigned long long Rw[16];
    __shared__ unsigned long long keepw[16];
    __shared__ int keptlist[64];
    __shared__ int s_kc;

    // ---- compact this level's valid boxes, preserving sorted order ----
    int base = tid * 18;                     // 18*256 = 4608 >= PAD
    int c = 0;
    #pragma unroll
    for (int k = 0; k < 18; ++k) {
        int r = base + k;
        if (r < PAD && sinfo[n * PAD + r] == l) ++c;
    }
    scan[tid] = c;
    __syncthreads();
    for (int d = 1; d < 256; d <<= 1) {
        int v = (tid >= d) ? scan[tid - d] : 0;
        __syncthreads();
        scan[tid] += v;
        __syncthreads();
    }
    int cnt = scan[255];
    int pos = scan[tid] - c;                 // exclusive prefix
    #pragma unroll
    for (int k = 0; k < 18; ++k) {
        int r = base + k;
        if (r < PAD && sinfo[n * PAD + r] == l) {
            lbox[pos] = sbn[n * PAD + r];
            lrank[pos] = (short)r;
            ++pos;
        }
    }
    for (int j = tid; j < 16; j += 256) { Rw[j] = 0; keepw[j] = 0; }
    __syncthreads();

    int nw = (cnt + 63) / 64;
    for (int cc = 0; cc < nw; ++cc) {
        int nb = min(64, cnt - cc * 64);
        // diagonal 64x64 IoU via ballot; wave w computes rows w*16..w*16+15
        float4 B = (lane < nb) ? lbox[cc * 64 + lane] : make_float4(0.f, 0.f, 0.f, 0.f);
        float a2 = (B.z - B.x) * (B.w - B.y);
        for (int t = 0; t < 16; ++t) {
            int i = w * 16 + t;
            if (i < nb) {
                float4 A = lbox[cc * 64 + i];
                float a1 = (A.z - A.x) * (A.w - A.y);
                float ltx = fmaxf(A.x, B.x), lty = fmaxf(A.y, B.y);
                float rbx = fminf(A.z, B.z), rby = fminf(A.w, B.w);
                float wx = fmaxf(rbx - ltx, 0.f), wy = fmaxf(rby - lty, 0.f);
                float inter = wx * wy;
                float iou = inter / ((a1 + a2) - inter);
                unsigned long long word = __ballot(iou > 0.7f);
                if (lane == 0) Dg[i] = word;
            }
        }
        __syncthreads();
        // serial resolve (wave 0, all lanes redundantly; LDS broadcast reads)
        if (w == 0) {
            unsigned long long Rc = Rw[cc];
            unsigned long long pend = ((nb == 64) ? ~0ull : ((1ull << nb) - 1ull)) & ~Rc;
            unsigned long long K = 0;
            int kc = 0;
            while (pend) {
                int b = __ffsll((long long)pend) - 1;
                K |= 1ull << b;
                if (lane == 0) keptlist[kc] = cc * 64 + b;
                ++kc;
                Rc |= Dg[b];
                pend &= ~Rc;
            }
            if (lane == 0) { s_kc = kc; keepw[cc] = K; }
        }
        __syncthreads();
        int kc = s_kc;
        // push: suppress later words with kept boxes (on-the-fly IoU)
        for (int jw = cc + 1 + w; jw < nw; jw += 4) {
            int nbj = min(64, cnt - jw * 64);
            float4 Bj = (lane < nbj) ? lbox[jw * 64 + lane] : make_float4(0.f, 0.f, 0.f, 0.f);
            float a2j = (Bj.z - Bj.x) * (Bj.w - Bj.y);
            bool acc = false;
            for (int e = 0; e < kc; ++e) {
                float4 A = lbox[keptlist[e]];
                float a1 = (A.z - A.x) * (A.w - A.y);
                float ltx = fmaxf(A.x, Bj.x), lty = fmaxf(A.y, Bj.y);
                float rbx = fminf(A.z, Bj.z), rby = fminf(A.w, Bj.w);
                float wx = fmaxf(rbx - ltx, 0.f), wy = fmaxf(rby - lty, 0.f);
                float inter = wx * wy;
                float iou = inter / ((a1 + a2j) - inter);
                acc = acc || (iou > 0.7f);
            }
            unsigned long long word = __ballot(acc);
            if (lane == 0) Rw[jw] |= word;    // jw owned by this wave: no race
        }
        __syncthreads();
    }
    // emit keep bits back to global sorted positions
    for (int m = tid; m < nw * 64; m += 256) {
        int cc = m >> 6, b = m & 63;
        if ((keepw[cc] >> b) & 1ull) {
            int r = (int)lrank[m];
            atomicOr(&keepmask[n * CH + (r >> 6)], 1ull << (r & 63));
        }
    }
}

// --------------- emit first 1000 kept (score order) -------------------------
__global__ __launch_bounds__(256) void k_epi(const unsigned long long* keepmask,
                                             const float4* sbox, const float* slog,
                                             float* out) {
    int n = blockIdx.x, tid = threadIdx.x;
    __shared__ unsigned long long kw[CH];
    __shared__ int pref[CH];
    if (tid < CH) kw[tid] = keepmask[n * CH + tid];
    __syncthreads();
    if (tid == 0) {
        int run = 0;
        for (int w2 = 0; w2 < CH; ++w2) { pref[w2] = run; run += __popcll(kw[w2]); }
    }
    __syncthreads();
    for (int i = tid; i < NSEL; i += 256) {
        int q = i >> 6, b = i & 63;
        if ((kw[q] >> b) & 1ull) {
            int rank = pref[q] + __popcll(kw[q] & ((1ull << b) - 1ull));
            if (rank < POSTN) {
                float4 bx = sbox[n * PAD + i];
                float lg = slog[n * PAD + i];
                ((float4*)out)[n * POSTN + rank] = bx;
                out[NIMG * POSTN * 4 + n * POSTN + rank] = 1.0f / (1.0f + expf(-lg));
            }
        }
    }
}

extern "C" void kernel_launch(void* const* d_in, const int* in_sizes, int n_in,
                              void* d_out, int out_size, void* d_ws, size_t ws_size,
                              hipStream_t stream) {
    Ptrs P;
    bool interleaved = (in_sizes[1] == 4 * in_sizes[0]);  // obj0,delta0,obj1,... vs obj0..4,delta0..4
    for (int i = 0; i < NLV; ++i) {
        if (interleaved) {
            P.obj[i] = (const float*)d_in[2 * i];
            P.del[i] = (const float*)d_in[2 * i + 1];
        } else {
            P.obj[i] = (const float*)d_in[i];
            P.del[i] = (const float*)d_in[NLV + i];
        }
    }
    P.anch = (const float*)d_in[10];

    char* w = (char*)d_ws;
    size_t off = 0;
    auto alloc = [&](size_t bytes) {
        void* p = w + off;
        off = (off + bytes + 255) & ~(size_t)255;
        return p;
    };
    unsigned long long* keepmask = (unsigned long long*)alloc((size_t)NIMG * CH * 8);
    int* cg      = (int*)alloc((size_t)TSEL * 4);
    float* cl    = (float*)alloc((size_t)TSEL * 4);
    unsigned long long* keys = (unsigned long long*)alloc((size_t)TSEL * 8);
    float4* recbox = (float4*)alloc((size_t)TSEL * 16);
    float4* recbn  = (float4*)alloc((size_t)TSEL * 16);
    float4* sbox = (float4*)alloc((size_t)NIMG * PAD * 16);
    float4* sbn  = (float4*)alloc((size_t)NIMG * PAD * 16);
    float* slog  = (float*)alloc((size_t)NIMG * PAD * 4);
    int* sinfo   = (int*)alloc((size_t)NIMG * PAD * 4);
    (void)ws_size; (void)n_in;

    (void)hipMemsetAsync(d_out, 0, (size_t)out_size * 4, stream);
    (void)hipMemsetAsync(keepmask, 0, (size_t)NIMG * CH * 8, stream);

    k_select<<<NIMG * NLV, 1024, 0, stream>>>(P, cg, cl);
    k_build<<<(TSEL + 255) / 256, 256, 0, stream>>>(P, cg, cl, keys, recbox, recbn);
    k_sort<<<NIMG, 1024, 0, stream>>>(keys, recbox, recbn, cl, sbox, sbn, slog, sinfo);
    k_nms<<<dim3(NLV, NIMG), 256, 0, stream>>>(sbn, sinfo, keepmask);
    k_epi<<<NIMG, 256, 0, stream>>>(keepmask, sbox, slog, (float*)d_out);
}

// Round 5
// 523.077 us; speedup vs baseline: 4.0527x; 1.5119x over previous
//
#include <hip/hip_runtime.h>
#include <cstdint>
#include <cstddef>

#define NLV 5
#define NIMG 4
#define NSEL 4507          // 1000+1000+1000+1000+507 selected per image
#define TSEL (NIMG * NSEL)
#define CH 71              // ceil(4507/64)
#define PAD (CH * 64)      // 4544
#define POSTN 1000
#define TIECAP 2048

__device__ const int d_W[NLV]    = {200, 100, 50, 25, 13};
__device__ const int d_NL[NLV]   = {120000, 30000, 7500, 1875, 507};
__device__ const int d_KOFF[6]   = {0, 120000, 150000, 157500, 159375, 159882};
__device__ const int d_LOFF[6]   = {0, 1000, 2000, 3000, 4000, 4507};
__device__ const int d_KL[NLV]   = {1000, 1000, 1000, 1000, 507};

struct Ptrs {
    const float* obj[NLV];
    const float* del[NLV];
    const float* anch;
};

// order-preserving map: dk ascending <=> float descending
__device__ inline unsigned int dkey_of(float f) {
    unsigned int u = __float_as_uint(f);
    unsigned int mk = (u & 0x80000000u) ? ~u : (u | 0x80000000u);
    return ~mk;
}
__device__ inline float logit_from_dkey(unsigned int dk) {
    unsigned int mk = ~dk;
    unsigned int u = (mk & 0x80000000u) ? (mk & 0x7fffffffu) : ~mk;
    return __uint_as_float(u);
}

// ---------------- per-(image,level) exact top-k selection -------------------
__global__ __launch_bounds__(1024) void k_select(Ptrs P, int* cg, float* cl) {
    __shared__ unsigned int hist[2048];
    __shared__ unsigned int cum[2048];
    __shared__ int tiebuf[TIECAP];
    __shared__ unsigned int s_bin, s_before;
    __shared__ int s_selc, s_tiec;

    int bx = blockIdx.x;
    int n = bx / NLV, l = bx % NLV;
    int tid = threadIdx.x;
    int Wl = d_W[l];
    int HW = Wl * Wl;
    int nl = d_NL[l];
    int kl = d_KL[l];
    const float* ob = P.obj[l] + (size_t)n * nl;
    int cbase = n * NSEL + d_LOFF[l];
    int koff = d_KOFF[l];

    if (kl >= nl) {  // level 4: take everything, deterministic slots
        for (int t = tid; t < nl; t += 1024) {
            int a = t / HW, rem = t - a * HW;
            int p = rem * 3 + a;
            cg[cbase + p] = koff + p;
            cl[cbase + p] = ob[t];
        }
        return;
    }

    unsigned int target = (unsigned int)kl;
    unsigned int b0, b1, b2, cnt_lt;

    auto scanfind = [&](unsigned int tgt) {
        int e0 = tid, e1 = tid + 1024;
        cum[e0] = hist[e0]; cum[e1] = hist[e1];
        __syncthreads();
        for (int d = 1; d < 2048; d <<= 1) {
            unsigned int v0 = (e0 >= d) ? cum[e0 - d] : 0u;
            unsigned int v1 = (e1 >= d) ? cum[e1 - d] : 0u;
            __syncthreads();
            cum[e0] += v0; cum[e1] += v1;
            __syncthreads();
        }
        for (int e = tid; e < 2048; e += 1024) {
            unsigned int inc = cum[e], exc = inc - hist[e];
            if (exc < tgt && tgt <= inc) { s_bin = (unsigned int)e; s_before = exc; }
        }
        __syncthreads();
    };

    // pass 1: bits [31:21]
    hist[tid] = 0; hist[tid + 1024] = 0; __syncthreads();
    for (int t = tid; t < nl; t += 1024)
        atomicAdd(&hist[dkey_of(ob[t]) >> 21], 1u);
    __syncthreads();
    scanfind(target);
    b0 = s_bin; cnt_lt = s_before;
    unsigned int t2 = target - s_before;
    __syncthreads();

    // pass 2: bits [20:10]
    hist[tid] = 0; hist[tid + 1024] = 0; __syncthreads();
    for (int t = tid; t < nl; t += 1024) {
        unsigned int dk = dkey_of(ob[t]);
        if ((dk >> 21) == b0) atomicAdd(&hist[(dk >> 10) & 0x7ffu], 1u);
    }
    __syncthreads();
    scanfind(t2);
    b1 = s_bin; cnt_lt += s_before;
    unsigned int t3 = t2 - s_before;
    __syncthreads();

    // pass 3: bits [9:0]
    hist[tid] = 0; hist[tid + 1024] = 0; __syncthreads();
    unsigned int pre22 = (b0 << 11) | b1;
    for (int t = tid; t < nl; t += 1024) {
        unsigned int dk = dkey_of(ob[t]);
        if ((dk >> 10) == pre22) atomicAdd(&hist[dk & 0x3ffu], 1u);
    }
    __syncthreads();
    scanfind(t3);
    b2 = s_bin; cnt_lt += s_before;
    unsigned int D = (b0 << 21) | (b1 << 10) | b2;
    int need = (int)(target - cnt_lt);

    // pass 4: selection + tie collection
    if (tid == 0) { s_selc = 0; s_tiec = 0; }
    __syncthreads();
    for (int t = tid; t < nl; t += 1024) {
        float lg = ob[t];
        unsigned int dk = dkey_of(lg);
        if (dk < D) {
            int pos = atomicAdd(&s_selc, 1);
            int a = t / HW, rem = t - a * HW;
            int p = rem * 3 + a;
            cg[cbase + pos] = koff + p;
            cl[cbase + pos] = lg;
        } else if (dk == D) {
            int tp = atomicAdd(&s_tiec, 1);
            if (tp < TIECAP) {
                int a = t / HW, rem = t - a * HW;
                tiebuf[tp] = rem * 3 + a;
            }
        }
    }
    __syncthreads();
    // pass 5: boundary ties, lowest indices first (top_k tie rule)
    int nt = min(s_tiec, TIECAP);
    float tlg = logit_from_dkey(D);
    for (int ti = tid; ti < nt; ti += 1024) {
        int myp = tiebuf[ti];
        int rank = 0;
        for (int j2 = 0; j2 < nt; ++j2) rank += (tiebuf[j2] < myp) ? 1 : 0;
        if (rank < need) {
            int pos = atomicAdd(&s_selc, 1);
            cg[cbase + pos] = koff + myp;
            cl[cbase + pos] = tlg;
        }
    }
}

// --------------- decode, clip, validity, sort key ---------------------------
__global__ __launch_bounds__(256) void k_build(Ptrs P, const int* cg, const float* cl,
                                               unsigned long long* keys,
                                               float4* recbox, float4* recbn) {
#pragma clang fp contract(off)
    int s = blockIdx.x * blockDim.x + threadIdx.x;
    if (s >= TSEL) return;
    int n = s / NSEL, r = s - n * NSEL;
    int gidx = cg[s];
    float lg = cl[s];
    int l = 0;
    while (l < 4 && gidx >= d_KOFF[l + 1]) ++l;
    int p = gidx - d_KOFF[l];
    int Wl = d_W[l];
    int HW = Wl * Wl;
    int a = p % 3, hw = p / 3;
    int h = hw / Wl, w = hw - h * Wl;
    const float* dl = P.del[l];
    size_t base = (size_t)(n * 12 + a * 4) * HW + (size_t)h * Wl + w;
    float dx = dl[base], dy = dl[base + HW];
    float dw = dl[base + 2 * (size_t)HW], dh = dl[base + 3 * (size_t)HW];
    const float* an = P.anch + 4 * (size_t)gidx;
    float ax1 = an[0], ay1 = an[1], ax2 = an[2], ay2 = an[3];
    float wa = ax2 - ax1, ha = ay2 - ay1;
    float cxa = ax1 + 0.5f * wa, cya = ay1 + 0.5f * ha;
    const float CLIPC = (float)4.135166556742356;
    dw = fminf(dw, CLIPC); dh = fminf(dh, CLIPC);
    float cx = dx * wa + cxa;
    float cy = dy * ha + cya;
    float ww = expf(dw) * wa;
    float hh = expf(dh) * ha;
    float x1 = cx - 0.5f * ww, y1 = cy - 0.5f * hh;
    float x2 = cx + 0.5f * ww, y2 = cy + 0.5f * hh;
    x1 = fminf(fmaxf(x1, 0.0f), 800.0f);
    y1 = fminf(fmaxf(y1, 0.0f), 800.0f);
    x2 = fminf(fmaxf(x2, 0.0f), 800.0f);
    y2 = fminf(fmaxf(y2, 0.0f), 800.0f);
    bool valid = (x2 - x1 >= 1e-3f) && (y2 - y1 >= 1e-3f);
    float off = (float)l * 801.0f;
    recbox[s] = make_float4(x1, y1, x2, y2);
    recbn[s] = make_float4(x1 + off, y1 + off, x2 + off, y2 + off);
    unsigned int sk = valid ? dkey_of(lg) : 0xffffffffu;
    keys[s] = ((unsigned long long)sk << 31) |
              ((unsigned long long)(unsigned int)gidx << 13) |
              (unsigned long long)r;
}

// --------------- per-image bitonic sort (8192 in LDS) -----------------------
__global__ __launch_bounds__(1024) void k_sort(const unsigned long long* keys,
                                               const float4* recbox, const float4* recbn,
                                               const float* cl,
                                               float4* sbox, float4* sbn, float* slog,
                                               int* sinfo) {
    __shared__ unsigned long long s[8192];
    int n = blockIdx.x, tid = threadIdx.x;
    for (int e = tid; e < 8192; e += 1024)
        s[e] = (e < NSEL) ? keys[n * NSEL + e] : 0xffffffffffffffffull;
    __syncthreads();
    for (int k = 2; k <= 8192; k <<= 1) {
        for (int j = k >> 1; j > 0; j >>= 1) {
            for (int pp = tid; pp < 4096; pp += 1024) {
                int i = ((pp & ~(j - 1)) << 1) | (pp & (j - 1));
                int ix = i | j;
                bool up = ((i & k) == 0);
                unsigned long long A = s[i], B = s[ix];
                if ((A > B) == up) { s[i] = B; s[ix] = A; }
            }
            __syncthreads();
        }
    }
    for (int r = tid; r < PAD; r += 1024) {
        if (r < NSEL) {
            unsigned long long key = s[r];
            int pos = (int)(key & 0x1fffull);
            int src = n * NSEL + pos;
            sbox[n * PAD + r] = recbox[src];
            sbn[n * PAD + r] = recbn[src];
            slog[n * PAD + r] = cl[src];
            bool valid = ((unsigned int)(key >> 31) != 0xffffffffu);
            int lvl = (pos >= 4000) ? 4 : (pos >= 3000) ? 3 : (pos >= 2000) ? 2
                      : (pos >= 1000) ? 1 : 0;
            sinfo[n * PAD + r] = valid ? lvl : -1;
        } else {
            sbox[n * PAD + r] = make_float4(0.f, 0.f, 0.f, 0.f);
            sbn[n * PAD + r] = make_float4(0.f, 0.f, 0.f, 0.f);
            slog[n * PAD + r] = 0.f;
            sinfo[n * PAD + r] = -1;
        }
    }
}

// --------------- per-(image,level) LDS-resident greedy NMS ------------------
// Cross-level IoU is exactly 0 (level*801 offsets, boxes clipped to [0,800]),
// so greedy NMS decomposes exactly into 5 per-level problems. 16 waves/block:
// diagonal 64x64 IoU via ballot; serial resolve in wave-0 REGISTERS
// (readlane, no LDS in the chain); kept boxes compacted to kbox[] so the
// suppression push reads sequential LDS with 4-wide unrolled b128 loads.
// NOTE: __builtin_amdgcn_readlane returns SIGNED int — must cast through
// (unsigned int) before widening to u64 or bit31 sign-extends (round-4 bug).
__global__ __launch_bounds__(1024) void k_nms(const float4* sbn, const int* sinfo,
                                              unsigned long long* keepmask) {
#pragma clang fp contract(off)
    int l = blockIdx.x, n = blockIdx.y;
    int tid = threadIdx.x, w = tid >> 6, lane = tid & 63;
    __shared__ float4 lbox[1024];
    __shared__ float4 kbox[64];
    __shared__ short lrank[1024];
    __shared__ int scan[1024];
    __shared__ unsigned long long Dg[64];
    __shared__ unsigned long long Rw[16];
    __shared__ unsigned long long keepw[16];
    __shared__ int s_kc;

    // ---- compact this level's valid boxes, preserving sorted order ----
    int base = tid * 5;                      // 5*1024 = 5120 >= PAD
    int c = 0;
    #pragma unroll
    for (int k = 0; k < 5; ++k) {
        int r = base + k;
        if (r < PAD && sinfo[n * PAD + r] == l) ++c;
    }
    scan[tid] = c;
    __syncthreads();
    for (int d = 1; d < 1024; d <<= 1) {
        int v = (tid >= d) ? scan[tid - d] : 0;
        __syncthreads();
        scan[tid] += v;
        __syncthreads();
    }
    int cnt = scan[1023];
    int pos = scan[tid] - c;                 // exclusive prefix
    #pragma unroll
    for (int k = 0; k < 5; ++k) {
        int r = base + k;
        if (r < PAD && sinfo[n * PAD + r] == l) {
            lbox[pos] = sbn[n * PAD + r];
            lrank[pos] = (short)r;
            ++pos;
        }
    }
    if (tid < 16) { Rw[tid] = 0; keepw[tid] = 0; }
    __syncthreads();

    int nw = (cnt + 63) / 64;
    for (int cc = 0; cc < nw; ++cc) {
        int nb = min(64, cnt - cc * 64);
        // diagonal 64x64 IoU via ballot; wave w computes rows w*4..w*4+3
        float4 B = (lane < nb) ? lbox[cc * 64 + lane] : make_float4(0.f, 0.f, 0.f, 0.f);
        float a2 = (B.z - B.x) * (B.w - B.y);
        #pragma unroll
        for (int t = 0; t < 4; ++t) {
            int i = w * 4 + t;
            if (i < nb) {
                float4 A = lbox[cc * 64 + i];
                float a1 = (A.z - A.x) * (A.w - A.y);
                float ltx = fmaxf(A.x, B.x), lty = fmaxf(A.y, B.y);
                float rbx = fminf(A.z, B.z), rby = fminf(A.w, B.w);
                float wx = fmaxf(rbx - ltx, 0.f), wy = fmaxf(rby - lty, 0.f);
                float inter = wx * wy;
                float iou = inter / ((a1 + a2) - inter);
                unsigned long long word = __ballot(iou > 0.7f);
                if (lane == 0) Dg[i] = word;
            }
        }
        __syncthreads();
        // serial resolve: wave 0, diagonal matrix in registers, readlane chain
        if (w == 0) {
            unsigned long long Dreg = (lane < nb) ? Dg[lane] : 0ull;
            unsigned int dlo = (unsigned int)Dreg;
            unsigned int dhi = (unsigned int)(Dreg >> 32);
            unsigned long long Rc = Rw[cc];
            unsigned long long pend = ((nb == 64) ? ~0ull : ((1ull << nb) - 1ull)) & ~Rc;
            unsigned long long K = 0;
            while (pend) {
                int b = __ffsll((long long)pend) - 1;
                K |= 1ull << b;
                unsigned long long row =
                    ((unsigned long long)(unsigned int)__builtin_amdgcn_readlane(dhi, b) << 32) |
                    (unsigned long long)(unsigned int)__builtin_amdgcn_readlane(dlo, b);
                Rc |= row;                   // self-bit set (iou=1): clears b from pend
                pend &= ~Rc;
            }
            // parallel compaction of kept boxes into kbox (dense, in order)
            if ((K >> lane) & 1ull)
                kbox[__popcll(K & ((1ull << lane) - 1ull))] = lbox[cc * 64 + lane];
            if (lane == 0) { s_kc = (int)__popcll(K); keepw[cc] = K; }
        }
        __syncthreads();
        int kc = s_kc;
        // push: wave w suppresses word cc+1+w (nw <= 16, one word per wave)
        int jw = cc + 1 + w;
        if (jw < nw && kc > 0) {
            int nbj = min(64, cnt - jw * 64);
            float4 Bj = (lane < nbj) ? lbox[jw * 64 + lane] : make_float4(0.f, 0.f, 0.f, 0.f);
            float a2j = (Bj.z - Bj.x) * (Bj.w - Bj.y);
            bool acc = false;
            int e = 0;
            for (; e + 3 < kc; e += 4) {      // 4 independent b128 reads pipeline
                float4 A0 = kbox[e], A1 = kbox[e + 1], A2 = kbox[e + 2], A3 = kbox[e + 3];
                {
                    float a1 = (A0.z - A0.x) * (A0.w - A0.y);
                    float ltx = fmaxf(A0.x, Bj.x), lty = fmaxf(A0.y, Bj.y);
                    float rbx = fminf(A0.z, Bj.z), rby = fminf(A0.w, Bj.w);
                    float wx = fmaxf(rbx - ltx, 0.f), wy = fmaxf(rby - lty, 0.f);
                    float inter = wx * wy;
                    acc = acc || (inter / ((a1 + a2j) - inter) > 0.7f);
                }
                {
                    float a1 = (A1.z - A1.x) * (A1.w - A1.y);
                    float ltx = fmaxf(A1.x, Bj.x), lty = fmaxf(A1.y, Bj.y);
                    float rbx = fminf(A1.z, Bj.z), rby = fminf(A1.w, Bj.w);
                    float wx = fmaxf(rbx - ltx, 0.f), wy = fmaxf(rby - lty, 0.f);
                    float inter = wx * wy;
                    acc = acc || (inter / ((a1 + a2j) - inter) > 0.7f);
                }
                {
                    float a1 = (A2.z - A2.x) * (A2.w - A2.y);
                    float ltx = fmaxf(A2.x, Bj.x), lty = fmaxf(A2.y, Bj.y);
                    float rbx = fminf(A2.z, Bj.z), rby = fminf(A2.w, Bj.w);
                    float wx = fmaxf(rbx - ltx, 0.f), wy = fmaxf(rby - lty, 0.f);
                    float inter = wx * wy;
                    acc = acc || (inter / ((a1 + a2j) - inter) > 0.7f);
                }
                {
                    float a1 = (A3.z - A3.x) * (A3.w - A3.y);
                    float ltx = fmaxf(A3.x, Bj.x), lty = fmaxf(A3.y, Bj.y);
                    float rbx = fminf(A3.z, Bj.z), rby = fminf(A3.w, Bj.w);
                    float wx = fmaxf(rbx - ltx, 0.f), wy = fmaxf(rby - lty, 0.f);
                    float inter = wx * wy;
                    acc = acc || (inter / ((a1 + a2j) - inter) > 0.7f);
                }
            }
            for (; e < kc; ++e) {
                float4 A = kbox[e];
                float a1 = (A.z - A.x) * (A.w - A.y);
                float ltx = fmaxf(A.x, Bj.x), lty = fmaxf(A.y, Bj.y);
                float rbx = fminf(A.z, Bj.z), rby = fminf(A.w, Bj.w);
                float wx = fmaxf(rbx - ltx, 0.f), wy = fmaxf(rby - lty, 0.f);
                float inter = wx * wy;
                acc = acc || (inter / ((a1 + a2j) - inter) > 0.7f);
            }
            unsigned long long word = __ballot(acc);
            if (lane == 0) Rw[jw] |= word;    // jw unique per wave: no race
        }
        __syncthreads();
    }
    // emit keep bits back to global sorted positions
    for (int m = tid; m < nw * 64; m += 1024) {
        int cc = m >> 6, b = m & 63;
        if ((keepw[cc] >> b) & 1ull) {
            int r = (int)lrank[m];
            atomicOr(&keepmask[n * CH + (r >> 6)], 1ull << (r & 63));
        }
    }
}

// --------------- emit first 1000 kept (score order) -------------------------
__global__ __launch_bounds__(256) void k_epi(const unsigned long long* keepmask,
                                             const float4* sbox, const float* slog,
                                             float* out) {
    int n = blockIdx.x, tid = threadIdx.x;
    __shared__ unsigned long long kw[CH];
    __shared__ int pref[CH];
    if (tid < CH) kw[tid] = keepmask[n * CH + tid];
    __syncthreads();
    if (tid == 0) {
        int run = 0;
        for (int w2 = 0; w2 < CH; ++w2) { pref[w2] = run; run += __popcll(kw[w2]); }
    }
    __syncthreads();
    for (int i = tid; i < NSEL; i += 256) {
        int q = i >> 6, b = i & 63;
        if ((kw[q] >> b) & 1ull) {
            int rank = pref[q] + __popcll(kw[q] & ((1ull << b) - 1ull));
            if (rank < POSTN) {
                float4 bx = sbox[n * PAD + i];
                float lg = slog[n * PAD + i];
                ((float4*)out)[n * POSTN + rank] = bx;
                out[NIMG * POSTN * 4 + n * POSTN + rank] = 1.0f / (1.0f + expf(-lg));
            }
        }
    }
}

extern "C" void kernel_launch(void* const* d_in, const int* in_sizes, int n_in,
                              void* d_out, int out_size, void* d_ws, size_t ws_size,
                              hipStream_t stream) {
    Ptrs P;
    bool interleaved = (in_sizes[1] == 4 * in_sizes[0]);  // obj0,delta0,obj1,... vs obj0..4,delta0..4
    for (int i = 0; i < NLV; ++i) {
        if (interleaved) {
            P.obj[i] = (const float*)d_in[2 * i];
            P.del[i] = (const float*)d_in[2 * i + 1];
        } else {
            P.obj[i] = (const float*)d_in[i];
            P.del[i] = (const float*)d_in[NLV + i];
        }
    }
    P.anch = (const float*)d_in[10];

    char* w = (char*)d_ws;
    size_t off = 0;
    auto alloc = [&](size_t bytes) {
        void* p = w + off;
        off = (off + bytes + 255) & ~(size_t)255;
        return p;
    };
    unsigned long long* keepmask = (unsigned long long*)alloc((size_t)NIMG * CH * 8);
    int* cg      = (int*)alloc((size_t)TSEL * 4);
    float* cl    = (float*)alloc((size_t)TSEL * 4);
    unsigned long long* keys = (unsigned long long*)alloc((size_t)TSEL * 8);
    float4* recbox = (float4*)alloc((size_t)TSEL * 16);
    float4* recbn  = (float4*)alloc((size_t)TSEL * 16);
    float4* sbox = (float4*)alloc((size_t)NIMG * PAD * 16);
    float4* sbn  = (float4*)alloc((size_t)NIMG * PAD * 16);
    float* slog  = (float*)alloc((size_t)NIMG * PAD * 4);
    int* sinfo   = (int*)alloc((size_t)NIMG * PAD * 4);
    (void)ws_size; (void)n_in;

    (void)hipMemsetAsync(d_out, 0, (size_t)out_size * 4, stream);
    (void)hipMemsetAsync(keepmask, 0, (size_t)NIMG * CH * 8, stream);

    k_select<<<NIMG * NLV, 1024, 0, stream>>>(P, cg, cl);
    k_build<<<(TSEL + 255) / 256, 256, 0, stream>>>(P, cg, cl, keys, recbox, recbn);
    k_sort<<<NIMG, 1024, 0, stream>>>(keys, recbox, recbn, cl, sbox, sbn, slog, sinfo);
    k_nms<<<dim3(NLV, NIMG), 1024, 0, stream>>>(sbn, sinfo, keepmask);
    k_epi<<<NIMG, 256, 0, stream>>>(keepmask, sbox, slog, (float*)d_out);
}

// Round 6
// 515.835 us; speedup vs baseline: 4.1096x; 1.0140x over previous
//
#include <hip/hip_runtime.h>
#include <cstdint>
#include <cstddef>

#define NLV 5
#define NIMG 4
#define NSEL 4507          // 1000+1000+1000+1000+507 selected per image
#define TSEL (NIMG * NSEL)
#define CH 71              // ceil(4507/64)
#define PAD (CH * 64)      // 4544
#define POSTN 1000
#define TIECAP 2048

__device__ const int d_W[NLV]    = {200, 100, 50, 25, 13};
__device__ const int d_NL[NLV]   = {120000, 30000, 7500, 1875, 507};
__device__ const int d_KOFF[6]   = {0, 120000, 150000, 157500, 159375, 159882};
__device__ const int d_LOFF[6]   = {0, 1000, 2000, 3000, 4000, 4507};
__device__ const int d_KL[NLV]   = {1000, 1000, 1000, 1000, 507};

struct Ptrs {
    const float* obj[NLV];
    const float* del[NLV];
    const float* anch;
};

// order-preserving map: dk ascending <=> float descending
__device__ inline unsigned int dkey_of(float f) {
    unsigned int u = __float_as_uint(f);
    unsigned int mk = (u & 0x80000000u) ? ~u : (u | 0x80000000u);
    return ~mk;
}
__device__ inline float logit_from_dkey(unsigned int dk) {
    unsigned int mk = ~dk;
    unsigned int u = (mk & 0x80000000u) ? (mk & 0x7fffffffu) : ~mk;
    return __uint_as_float(u);
}

// ---------------- per-(image,level) exact top-k selection -------------------
__global__ __launch_bounds__(1024) void k_select(Ptrs P, int* cg, float* cl) {
    __shared__ unsigned int hist[2048];
    __shared__ unsigned int cum[2048];
    __shared__ int tiebuf[TIECAP];
    __shared__ unsigned int s_bin, s_before;
    __shared__ int s_selc, s_tiec;

    int bx = blockIdx.x;
    int n = bx / NLV, l = bx % NLV;
    int tid = threadIdx.x;
    int Wl = d_W[l];
    int HW = Wl * Wl;
    int nl = d_NL[l];
    int kl = d_KL[l];
    const float* ob = P.obj[l] + (size_t)n * nl;
    int cbase = n * NSEL + d_LOFF[l];
    int koff = d_KOFF[l];

    if (kl >= nl) {  // level 4: take everything, deterministic slots
        for (int t = tid; t < nl; t += 1024) {
            int a = t / HW, rem = t - a * HW;
            int p = rem * 3 + a;
            cg[cbase + p] = koff + p;
            cl[cbase + p] = ob[t];
        }
        return;
    }

    unsigned int target = (unsigned int)kl;
    unsigned int b0, b1, b2, cnt_lt;

    auto scanfind = [&](unsigned int tgt) {
        int e0 = tid, e1 = tid + 1024;
        cum[e0] = hist[e0]; cum[e1] = hist[e1];
        __syncthreads();
        for (int d = 1; d < 2048; d <<= 1) {
            unsigned int v0 = (e0 >= d) ? cum[e0 - d] : 0u;
            unsigned int v1 = (e1 >= d) ? cum[e1 - d] : 0u;
            __syncthreads();
            cum[e0] += v0; cum[e1] += v1;
            __syncthreads();
        }
        for (int e = tid; e < 2048; e += 1024) {
            unsigned int inc = cum[e], exc = inc - hist[e];
            if (exc < tgt && tgt <= inc) { s_bin = (unsigned int)e; s_before = exc; }
        }
        __syncthreads();
    };

    // pass 1: bits [31:21]
    hist[tid] = 0; hist[tid + 1024] = 0; __syncthreads();
    for (int t = tid; t < nl; t += 1024)
        atomicAdd(&hist[dkey_of(ob[t]) >> 21], 1u);
    __syncthreads();
    scanfind(target);
    b0 = s_bin; cnt_lt = s_before;
    unsigned int t2 = target - s_before;
    __syncthreads();

    // pass 2: bits [20:10]
    hist[tid] = 0; hist[tid + 1024] = 0; __syncthreads();
    for (int t = tid; t < nl; t += 1024) {
        unsigned int dk = dkey_of(ob[t]);
        if ((dk >> 21) == b0) atomicAdd(&hist[(dk >> 10) & 0x7ffu], 1u);
    }
    __syncthreads();
    scanfind(t2);
    b1 = s_bin; cnt_lt += s_before;
    unsigned int t3 = t2 - s_before;
    __syncthreads();

    // pass 3: bits [9:0]
    hist[tid] = 0; hist[tid + 1024] = 0; __syncthreads();
    unsigned int pre22 = (b0 << 11) | b1;
    for (int t = tid; t < nl; t += 1024) {
        unsigned int dk = dkey_of(ob[t]);
        if ((dk >> 10) == pre22) atomicAdd(&hist[dk & 0x3ffu], 1u);
    }
    __syncthreads();
    scanfind(t3);
    b2 = s_bin; cnt_lt += s_before;
    unsigned int D = (b0 << 21) | (b1 << 10) | b2;
    int need = (int)(target - cnt_lt);

    // pass 4: selection + tie collection
    if (tid == 0) { s_selc = 0; s_tiec = 0; }
    __syncthreads();
    for (int t = tid; t < nl; t += 1024) {
        float lg = ob[t];
        unsigned int dk = dkey_of(lg);
        if (dk < D) {
            int pos = atomicAdd(&s_selc, 1);
            int a = t / HW, rem = t - a * HW;
            int p = rem * 3 + a;
            cg[cbase + pos] = koff + p;
            cl[cbase + pos] = lg;
        } else if (dk == D) {
            int tp = atomicAdd(&s_tiec, 1);
            if (tp < TIECAP) {
                int a = t / HW, rem = t - a * HW;
                tiebuf[tp] = rem * 3 + a;
            }
        }
    }
    __syncthreads();
    // pass 5: boundary ties, lowest indices first (top_k tie rule)
    int nt = min(s_tiec, TIECAP);
    float tlg = logit_from_dkey(D);
    for (int ti = tid; ti < nt; ti += 1024) {
        int myp = tiebuf[ti];
        int rank = 0;
        for (int j2 = 0; j2 < nt; ++j2) rank += (tiebuf[j2] < myp) ? 1 : 0;
        if (rank < need) {
            int pos = atomicAdd(&s_selc, 1);
            cg[cbase + pos] = koff + myp;
            cl[cbase + pos] = tlg;
        }
    }
}

// --------------- decode, clip, validity, sort key ---------------------------
// Also zero-inits keepmask (replaces a hipMemsetAsync dispatch).
__global__ __launch_bounds__(256) void k_build(Ptrs P, const int* cg, const float* cl,
                                               unsigned long long* keys,
                                               float4* recbox, float4* recbn,
                                               unsigned long long* keepmask) {
#pragma clang fp contract(off)
    int s = blockIdx.x * blockDim.x + threadIdx.x;
    if (s < NIMG * CH) keepmask[s] = 0ull;
    if (s >= TSEL) return;
    int n = s / NSEL, r = s - n * NSEL;
    int gidx = cg[s];
    float lg = cl[s];
    int l = 0;
    while (l < 4 && gidx >= d_KOFF[l + 1]) ++l;
    int p = gidx - d_KOFF[l];
    int Wl = d_W[l];
    int HW = Wl * Wl;
    int a = p % 3, hw = p / 3;
    int h = hw / Wl, w = hw - h * Wl;
    const float* dl = P.del[l];
    size_t base = (size_t)(n * 12 + a * 4) * HW + (size_t)h * Wl + w;
    float dx = dl[base], dy = dl[base + HW];
    float dw = dl[base + 2 * (size_t)HW], dh = dl[base + 3 * (size_t)HW];
    const float* an = P.anch + 4 * (size_t)gidx;
    float ax1 = an[0], ay1 = an[1], ax2 = an[2], ay2 = an[3];
    float wa = ax2 - ax1, ha = ay2 - ay1;
    float cxa = ax1 + 0.5f * wa, cya = ay1 + 0.5f * ha;
    const float CLIPC = (float)4.135166556742356;
    dw = fminf(dw, CLIPC); dh = fminf(dh, CLIPC);
    float cx = dx * wa + cxa;
    float cy = dy * ha + cya;
    float ww = expf(dw) * wa;
    float hh = expf(dh) * ha;
    float x1 = cx - 0.5f * ww, y1 = cy - 0.5f * hh;
    float x2 = cx + 0.5f * ww, y2 = cy + 0.5f * hh;
    x1 = fminf(fmaxf(x1, 0.0f), 800.0f);
    y1 = fminf(fmaxf(y1, 0.0f), 800.0f);
    x2 = fminf(fmaxf(x2, 0.0f), 800.0f);
    y2 = fminf(fmaxf(y2, 0.0f), 800.0f);
    bool valid = (x2 - x1 >= 1e-3f) && (y2 - y1 >= 1e-3f);
    float off = (float)l * 801.0f;
    recbox[s] = make_float4(x1, y1, x2, y2);
    recbn[s] = make_float4(x1 + off, y1 + off, x2 + off, y2 + off);
    unsigned int sk = valid ? dkey_of(lg) : 0xffffffffu;
    keys[s] = ((unsigned long long)sk << 31) |
              ((unsigned long long)(unsigned int)gidx << 13) |
              (unsigned long long)r;
}

// --------------- per-image bitonic sort (8192 in LDS) -----------------------
__global__ __launch_bounds__(1024) void k_sort(const unsigned long long* keys,
                                               const float4* recbox, const float4* recbn,
                                               const float* cl,
                                               float4* sbox, float4* sbn, float* slog,
                                               int* sinfo) {
    __shared__ unsigned long long s[8192];
    int n = blockIdx.x, tid = threadIdx.x;
    for (int e = tid; e < 8192; e += 1024)
        s[e] = (e < NSEL) ? keys[n * NSEL + e] : 0xffffffffffffffffull;
    __syncthreads();
    for (int k = 2; k <= 8192; k <<= 1) {
        for (int j = k >> 1; j > 0; j >>= 1) {
            for (int pp = tid; pp < 4096; pp += 1024) {
                int i = ((pp & ~(j - 1)) << 1) | (pp & (j - 1));
                int ix = i | j;
                bool up = ((i & k) == 0);
                unsigned long long A = s[i], B = s[ix];
                if ((A > B) == up) { s[i] = B; s[ix] = A; }
            }
            __syncthreads();
        }
    }
    for (int r = tid; r < PAD; r += 1024) {
        if (r < NSEL) {
            unsigned long long key = s[r];
            int pos = (int)(key & 0x1fffull);
            int src = n * NSEL + pos;
            sbox[n * PAD + r] = recbox[src];
            sbn[n * PAD + r] = recbn[src];
            slog[n * PAD + r] = cl[src];
            bool valid = ((unsigned int)(key >> 31) != 0xffffffffu);
            int lvl = (pos >= 4000) ? 4 : (pos >= 3000) ? 3 : (pos >= 2000) ? 2
                      : (pos >= 1000) ? 1 : 0;
            sinfo[n * PAD + r] = valid ? lvl : -1;
        } else {
            sbox[n * PAD + r] = make_float4(0.f, 0.f, 0.f, 0.f);
            sbn[n * PAD + r] = make_float4(0.f, 0.f, 0.f, 0.f);
            slog[n * PAD + r] = 0.f;
            sinfo[n * PAD + r] = -1;
        }
    }
}

// --------------- per-(image,level) LDS-resident greedy NMS ------------------
// Cross-level IoU is exactly 0 (level*801 offsets, boxes clipped to [0,800]),
// so greedy NMS decomposes exactly into 5 per-level problems.
// Round-6 structure: wave w computes chunk w's 64x64 diagonal UPFRONT into
// its own registers (parallel across 16 waves); the serial loop is then just
// {wave-cc register resolve -> barrier -> all-wave push -> barrier} = 2
// barriers/chunk and no LDS in the resolve chain (readlane + SALU).
// NOTE: __builtin_amdgcn_readlane returns SIGNED int — cast through
// (unsigned int) before widening to u64 (round-4 bug).
__global__ __launch_bounds__(1024) void k_nms(const float4* sbn, const int* sinfo,
                                              unsigned long long* keepmask) {
#pragma clang fp contract(off)
    int l = blockIdx.x, n = blockIdx.y;
    int tid = threadIdx.x, w = tid >> 6, lane = tid & 63;
    __shared__ float4 lbox[1024];
    __shared__ float4 kbox[64];
    __shared__ short lrank[1024];
    __shared__ int wsum[16];
    __shared__ unsigned long long Rw[16];
    __shared__ unsigned long long keepw[16];
    __shared__ int s_kc;

    // ---- compact this level's valid boxes, preserving sorted order ----
    int base = tid * 5;                      // 5*1024 = 5120 >= PAD
    bool hit[5];
    int c = 0;
    #pragma unroll
    for (int k = 0; k < 5; ++k) {
        int r = base + k;
        hit[k] = (r < PAD) && (sinfo[n * PAD + r] == l);
        c += hit[k] ? 1 : 0;
    }
    // per-wave inclusive scan (shfl, no barriers)
    int v = c;
    #pragma unroll
    for (int d2 = 1; d2 < 64; d2 <<= 1) {
        int t2 = __shfl_up(v, d2, 64);
        if (lane >= d2) v += t2;
    }
    if (lane == 63) wsum[w] = v;
    if (tid < 16) { Rw[tid] = 0; keepw[tid] = 0; }
    __syncthreads();
    int woff = 0, cnt = 0;
    #pragma unroll
    for (int ww = 0; ww < 16; ++ww) {
        int s2 = wsum[ww];
        if (ww < w) woff += s2;
        cnt += s2;
    }
    int pos = woff + v - c;                  // exclusive prefix
    #pragma unroll
    for (int k = 0; k < 5; ++k) {
        if (hit[k]) {
            lbox[pos] = sbn[n * PAD + (base + k)];
            lrank[pos] = (short)(base + k);
            ++pos;
        }
    }
    __syncthreads();

    int nw = (cnt + 63) / 64;

    // ---- upfront: wave w computes its chunk's diagonal into registers ----
    unsigned int dlo = 0, dhi = 0;
    if (w < nw) {
        int nbw = min(64, cnt - w * 64);
        float4 B = (lane < nbw) ? lbox[w * 64 + lane] : make_float4(0.f, 0.f, 0.f, 0.f);
        float a2 = (B.z - B.x) * (B.w - B.y);
        for (int i = 0; i < nbw; ++i) {
            float4 A = lbox[w * 64 + i];
            float a1 = (A.z - A.x) * (A.w - A.y);
            float ltx = fmaxf(A.x, B.x), lty = fmaxf(A.y, B.y);
            float rbx = fminf(A.z, B.z), rby = fminf(A.w, B.w);
            float wx = fmaxf(rbx - ltx, 0.f), wy = fmaxf(rby - lty, 0.f);
            float inter = wx * wy;
            float iou = inter / ((a1 + a2) - inter);
            unsigned long long word = __ballot(iou > 0.7f);
            if (lane == i) { dlo = (unsigned int)word; dhi = (unsigned int)(word >> 32); }
        }
    }
    // NOTE: no barrier needed — each wave only reads lbox it already sees
    // coherently (written before the last __syncthreads).

    for (int cc = 0; cc < nw; ++cc) {
        // resolve by wave cc on its register-resident diagonal
        if (w == cc) {
            int nb = min(64, cnt - cc * 64);
            unsigned long long Rc = Rw[cc];
            unsigned long long pend = ((nb == 64) ? ~0ull : ((1ull << nb) - 1ull)) & ~Rc;
            unsigned long long K = 0;
            while (pend) {
                int b = __builtin_amdgcn_readfirstlane(
                            (int)(__ffsll((long long)pend) - 1));
                K |= 1ull << b;
                unsigned long long row =
                    ((unsigned long long)(unsigned int)__builtin_amdgcn_readlane(dhi, b) << 32) |
                    (unsigned long long)(unsigned int)__builtin_amdgcn_readlane(dlo, b);
                Rc |= row;                   // self-bit set (iou=1): clears b from pend
                pend &= ~Rc;
            }
            // parallel compaction of kept boxes into kbox (dense, in order)
            if ((K >> lane) & 1ull)
                kbox[__popcll(K & ((1ull << lane) - 1ull))] = lbox[cc * 64 + lane];
            if (lane == 0) { s_kc = (int)__popcll(K); keepw[cc] = K; }
        }
        __syncthreads();
        int kc = s_kc;
        // push: wave w suppresses word cc+1+w (nw <= 16, one word per wave)
        int jw = cc + 1 + w;
        if (jw < nw && kc > 0) {
            int nbj = min(64, cnt - jw * 64);
            float4 Bj = (lane < nbj) ? lbox[jw * 64 + lane] : make_float4(0.f, 0.f, 0.f, 0.f);
            float a2j = (Bj.z - Bj.x) * (Bj.w - Bj.y);
            bool acc = false;
            int e = 0;
            for (; e + 3 < kc; e += 4) {      // 4 independent b128 reads pipeline
                float4 A0 = kbox[e], A1 = kbox[e + 1], A2 = kbox[e + 2], A3 = kbox[e + 3];
                {
                    float a1 = (A0.z - A0.x) * (A0.w - A0.y);
                    float ltx = fmaxf(A0.x, Bj.x), lty = fmaxf(A0.y, Bj.y);
                    float rbx = fminf(A0.z, Bj.z), rby = fminf(A0.w, Bj.w);
                    float wx = fmaxf(rbx - ltx, 0.f), wy = fmaxf(rby - lty, 0.f);
                    float inter = wx * wy;
                    acc = acc || (inter / ((a1 + a2j) - inter) > 0.7f);
                }
                {
                    float a1 = (A1.z - A1.x) * (A1.w - A1.y);
                    float ltx = fmaxf(A1.x, Bj.x), lty = fmaxf(A1.y, Bj.y);
                    float rbx = fminf(A1.z, Bj.z), rby = fminf(A1.w, Bj.w);
                    float wx = fmaxf(rbx - ltx, 0.f), wy = fmaxf(rby - lty, 0.f);
                    float inter = wx * wy;
                    acc = acc || (inter / ((a1 + a2j) - inter) > 0.7f);
                }
                {
                    float a1 = (A2.z - A2.x) * (A2.w - A2.y);
                    float ltx = fmaxf(A2.x, Bj.x), lty = fmaxf(A2.y, Bj.y);
                    float rbx = fminf(A2.z, Bj.z), rby = fminf(A2.w, Bj.w);
                    float wx = fmaxf(rbx - ltx, 0.f), wy = fmaxf(rby - lty, 0.f);
                    float inter = wx * wy;
                    acc = acc || (inter / ((a1 + a2j) - inter) > 0.7f);
                }
                {
                    float a1 = (A3.z - A3.x) * (A3.w - A3.y);
                    float ltx = fmaxf(A3.x, Bj.x), lty = fmaxf(A3.y, Bj.y);
                    float rbx = fminf(A3.z, Bj.z), rby = fminf(A3.w, Bj.w);
                    float wx = fmaxf(rbx - ltx, 0.f), wy = fmaxf(rby - lty, 0.f);
                    float inter = wx * wy;
                    acc = acc || (inter / ((a1 + a2j) - inter) > 0.7f);
                }
            }
            for (; e < kc; ++e) {
                float4 A = kbox[e];
                float a1 = (A.z - A.x) * (A.w - A.y);
                float ltx = fmaxf(A.x, Bj.x), lty = fmaxf(A.y, Bj.y);
                float rbx = fminf(A.z, Bj.z), rby = fminf(A.w, Bj.w);
                float wx = fmaxf(rbx - ltx, 0.f), wy = fmaxf(rby - lty, 0.f);
                float inter = wx * wy;
                acc = acc || (inter / ((a1 + a2j) - inter) > 0.7f);
            }
            unsigned long long word = __ballot(acc);
            if (lane == 0) Rw[jw] |= word;    // jw unique per wave: no race
        }
        __syncthreads();
    }
    // emit keep bits back to global sorted positions
    for (int m = tid; m < nw * 64; m += 1024) {
        int cc = m >> 6, b = m & 63;
        if ((keepw[cc] >> b) & 1ull) {
            int r = (int)lrank[m];
            atomicOr(&keepmask[n * CH + (r >> 6)], 1ull << (r & 63));
        }
    }
}

// --------------- zero-init + emit first 1000 kept (score order) -------------
__global__ __launch_bounds__(256) void k_epi(const unsigned long long* keepmask,
                                             const float4* sbox, const float* slog,
                                             float* out) {
    int n = blockIdx.x, tid = threadIdx.x;
    __shared__ unsigned long long kw[CH];
    __shared__ int pref[CH];
    // zero-init this image's output slice (replaces hipMemsetAsync)
    for (int i = tid; i < POSTN; i += 256) {
        ((float4*)out)[n * POSTN + i] = make_float4(0.f, 0.f, 0.f, 0.f);
        out[NIMG * POSTN * 4 + n * POSTN + i] = 0.f;
    }
    if (tid < CH) kw[tid] = keepmask[n * CH + tid];
    __syncthreads();
    if (tid == 0) {
        int run = 0;
        for (int w2 = 0; w2 < CH; ++w2) { pref[w2] = run; run += __popcll(kw[w2]); }
    }
    __syncthreads();
    for (int i = tid; i < NSEL; i += 256) {
        int q = i >> 6, b = i & 63;
        if ((kw[q] >> b) & 1ull) {
            int rank = pref[q] + __popcll(kw[q] & ((1ull << b) - 1ull));
            if (rank < POSTN) {
                float4 bx = sbox[n * PAD + i];
                float lg = slog[n * PAD + i];
                ((float4*)out)[n * POSTN + rank] = bx;
                out[NIMG * POSTN * 4 + n * POSTN + rank] = 1.0f / (1.0f + expf(-lg));
            }
        }
    }
}

extern "C" void kernel_launch(void* const* d_in, const int* in_sizes, int n_in,
                              void* d_out, int out_size, void* d_ws, size_t ws_size,
                              hipStream_t stream) {
    Ptrs P;
    bool interleaved = (in_sizes[1] == 4 * in_sizes[0]);  // obj0,delta0,obj1,... vs obj0..4,delta0..4
    for (int i = 0; i < NLV; ++i) {
        if (interleaved) {
            P.obj[i] = (const float*)d_in[2 * i];
            P.del[i] = (const float*)d_in[2 * i + 1];
        } else {
            P.obj[i] = (const float*)d_in[i];
            P.del[i] = (const float*)d_in[NLV + i];
        }
    }
    P.anch = (const float*)d_in[10];

    char* w = (char*)d_ws;
    size_t off = 0;
    auto alloc = [&](size_t bytes) {
        void* p = w + off;
        off = (off + bytes + 255) & ~(size_t)255;
        return p;
    };
    unsigned long long* keepmask = (unsigned long long*)alloc((size_t)NIMG * CH * 8);
    int* cg      = (int*)alloc((size_t)TSEL * 4);
    float* cl    = (float*)alloc((size_t)TSEL * 4);
    unsigned long long* keys = (unsigned long long*)alloc((size_t)TSEL * 8);
    float4* recbox = (float4*)alloc((size_t)TSEL * 16);
    float4* recbn  = (float4*)alloc((size_t)TSEL * 16);
    float4* sbox = (float4*)alloc((size_t)NIMG * PAD * 16);
    float4* sbn  = (float4*)alloc((size_t)NIMG * PAD * 16);
    float* slog  = (float*)alloc((size_t)NIMG * PAD * 4);
    int* sinfo   = (int*)alloc((size_t)NIMG * PAD * 4);
    (void)ws_size; (void)n_in;

    k_select<<<NIMG * NLV, 1024, 0, stream>>>(P, cg, cl);
    k_build<<<(TSEL + 255) / 256, 256, 0, stream>>>(P, cg, cl, keys, recbox, recbn, keepmask);
    k_sort<<<NIMG, 1024, 0, stream>>>(keys, recbox, recbn, cl, sbox, sbn, slog, sinfo);
    k_nms<<<dim3(NLV, NIMG), 1024, 0, stream>>>(sbn, sinfo, keepmask);
    k_epi<<<NIMG, 256, 0, stream>>>(keepmask, sbox, slog, (float*)d_out);
}

// Round 7
// 386.175 us; speedup vs baseline: 5.4895x; 1.3358x over previous
//
#include <hip/hip_runtime.h>
#include <cstdint>
#include <cstddef>

#define NLV 5
#define NIMG 4
#define NSEL 4507          // 1000+1000+1000+1000+507 selected per image
#define TSEL (NIMG * NSEL)
#define CH 71              // ceil(4507/64)
#define PAD (CH * 64)      // 4544
#define POSTN 1000
#define TIECAP 2048
#define NWMAX 16           // max 64-chunks per level (1000 -> 16)

__device__ const int d_W[NLV]    = {200, 100, 50, 25, 13};
__device__ const int d_NL[NLV]   = {120000, 30000, 7500, 1875, 507};
__device__ const int d_KOFF[6]   = {0, 120000, 150000, 157500, 159375, 159882};
__device__ const int d_LOFF[6]   = {0, 1000, 2000, 3000, 4000, 4507};
__device__ const int d_KL[NLV]   = {1000, 1000, 1000, 1000, 507};

struct Ptrs {
    const float* obj[NLV];
    const float* del[NLV];
    const float* anch;
};

// order-preserving map: dk ascending <=> float descending
__device__ inline unsigned int dkey_of(float f) {
    unsigned int u = __float_as_uint(f);
    unsigned int mk = (u & 0x80000000u) ? ~u : (u | 0x80000000u);
    return ~mk;
}
__device__ inline float logit_from_dkey(unsigned int dk) {
    unsigned int mk = ~dk;
    unsigned int u = (mk & 0x80000000u) ? (mk & 0x7fffffffu) : ~mk;
    return __uint_as_float(u);
}

// ---------------- per-(image,level) exact top-k selection -------------------
__global__ __launch_bounds__(1024) void k_select(Ptrs P, int* cg, float* cl) {
    __shared__ unsigned int hist[2048];
    __shared__ unsigned int cum[2048];
    __shared__ int tiebuf[TIECAP];
    __shared__ unsigned int s_bin, s_before;
    __shared__ int s_selc, s_tiec;

    int bx = blockIdx.x;
    int n = bx / NLV, l = bx % NLV;
    int tid = threadIdx.x;
    int Wl = d_W[l];
    int HW = Wl * Wl;
    int nl = d_NL[l];
    int kl = d_KL[l];
    const float* ob = P.obj[l] + (size_t)n * nl;
    int cbase = n * NSEL + d_LOFF[l];
    int koff = d_KOFF[l];

    if (kl >= nl) {  // level 4: take everything, deterministic slots
        for (int t = tid; t < nl; t += 1024) {
            int a = t / HW, rem = t - a * HW;
            int p = rem * 3 + a;
            cg[cbase + p] = koff + p;
            cl[cbase + p] = ob[t];
        }
        return;
    }

    unsigned int target = (unsigned int)kl;
    unsigned int b0, b1, b2, cnt_lt;

    auto scanfind = [&](unsigned int tgt) {
        int e0 = tid, e1 = tid + 1024;
        cum[e0] = hist[e0]; cum[e1] = hist[e1];
        __syncthreads();
        for (int d = 1; d < 2048; d <<= 1) {
            unsigned int v0 = (e0 >= d) ? cum[e0 - d] : 0u;
            unsigned int v1 = (e1 >= d) ? cum[e1 - d] : 0u;
            __syncthreads();
            cum[e0] += v0; cum[e1] += v1;
            __syncthreads();
        }
        for (int e = tid; e < 2048; e += 1024) {
            unsigned int inc = cum[e], exc = inc - hist[e];
            if (exc < tgt && tgt <= inc) { s_bin = (unsigned int)e; s_before = exc; }
        }
        __syncthreads();
    };

    // pass 1: bits [31:21]
    hist[tid] = 0; hist[tid + 1024] = 0; __syncthreads();
    for (int t = tid; t < nl; t += 1024)
        atomicAdd(&hist[dkey_of(ob[t]) >> 21], 1u);
    __syncthreads();
    scanfind(target);
    b0 = s_bin; cnt_lt = s_before;
    unsigned int t2 = target - s_before;
    __syncthreads();

    // pass 2: bits [20:10]
    hist[tid] = 0; hist[tid + 1024] = 0; __syncthreads();
    for (int t = tid; t < nl; t += 1024) {
        unsigned int dk = dkey_of(ob[t]);
        if ((dk >> 21) == b0) atomicAdd(&hist[(dk >> 10) & 0x7ffu], 1u);
    }
    __syncthreads();
    scanfind(t2);
    b1 = s_bin; cnt_lt += s_before;
    unsigned int t3 = t2 - s_before;
    __syncthreads();

    // pass 3: bits [9:0]
    hist[tid] = 0; hist[tid + 1024] = 0; __syncthreads();
    unsigned int pre22 = (b0 << 11) | b1;
    for (int t = tid; t < nl; t += 1024) {
        unsigned int dk = dkey_of(ob[t]);
        if ((dk >> 10) == pre22) atomicAdd(&hist[dk & 0x3ffu], 1u);
    }
    __syncthreads();
    scanfind(t3);
    b2 = s_bin; cnt_lt += s_before;
    unsigned int D = (b0 << 21) | (b1 << 10) | b2;
    int need = (int)(target - cnt_lt);

    // pass 4: selection + tie collection
    if (tid == 0) { s_selc = 0; s_tiec = 0; }
    __syncthreads();
    for (int t = tid; t < nl; t += 1024) {
        float lg = ob[t];
        unsigned int dk = dkey_of(lg);
        if (dk < D) {
            int pos = atomicAdd(&s_selc, 1);
            int a = t / HW, rem = t - a * HW;
            int p = rem * 3 + a;
            cg[cbase + pos] = koff + p;
            cl[cbase + pos] = lg;
        } else if (dk == D) {
            int tp = atomicAdd(&s_tiec, 1);
            if (tp < TIECAP) {
                int a = t / HW, rem = t - a * HW;
                tiebuf[tp] = rem * 3 + a;
            }
        }
    }
    __syncthreads();
    // pass 5: boundary ties, lowest indices first (top_k tie rule)
    int nt = min(s_tiec, TIECAP);
    float tlg = logit_from_dkey(D);
    for (int ti = tid; ti < nt; ti += 1024) {
        int myp = tiebuf[ti];
        int rank = 0;
        for (int j2 = 0; j2 < nt; ++j2) rank += (tiebuf[j2] < myp) ? 1 : 0;
        if (rank < need) {
            int pos = atomicAdd(&s_selc, 1);
            cg[cbase + pos] = koff + myp;
            cl[cbase + pos] = tlg;
        }
    }
}

// --------------- decode, clip, validity, sort key ---------------------------
// Also zero-inits keepmask (replaces a hipMemsetAsync dispatch).
__global__ __launch_bounds__(256) void k_build(Ptrs P, const int* cg, const float* cl,
                                               unsigned long long* keys,
                                               float4* recbox, float4* recbn,
                                               unsigned long long* keepmask) {
#pragma clang fp contract(off)
    int s = blockIdx.x * blockDim.x + threadIdx.x;
    if (s < NIMG * CH) keepmask[s] = 0ull;
    if (s >= TSEL) return;
    int n = s / NSEL, r = s - n * NSEL;
    int gidx = cg[s];
    float lg = cl[s];
    int l = 0;
    while (l < 4 && gidx >= d_KOFF[l + 1]) ++l;
    int p = gidx - d_KOFF[l];
    int Wl = d_W[l];
    int HW = Wl * Wl;
    int a = p % 3, hw = p / 3;
    int h = hw / Wl, w = hw - h * Wl;
    const float* dl = P.del[l];
    size_t base = (size_t)(n * 12 + a * 4) * HW + (size_t)h * Wl + w;
    float dx = dl[base], dy = dl[base + HW];
    float dw = dl[base + 2 * (size_t)HW], dh = dl[base + 3 * (size_t)HW];
    const float* an = P.anch + 4 * (size_t)gidx;
    float ax1 = an[0], ay1 = an[1], ax2 = an[2], ay2 = an[3];
    float wa = ax2 - ax1, ha = ay2 - ay1;
    float cxa = ax1 + 0.5f * wa, cya = ay1 + 0.5f * ha;
    const float CLIPC = (float)4.135166556742356;
    dw = fminf(dw, CLIPC); dh = fminf(dh, CLIPC);
    float cx = dx * wa + cxa;
    float cy = dy * ha + cya;
    float ww = expf(dw) * wa;
    float hh = expf(dh) * ha;
    float x1 = cx - 0.5f * ww, y1 = cy - 0.5f * hh;
    float x2 = cx + 0.5f * ww, y2 = cy + 0.5f * hh;
    x1 = fminf(fmaxf(x1, 0.0f), 800.0f);
    y1 = fminf(fmaxf(y1, 0.0f), 800.0f);
    x2 = fminf(fmaxf(x2, 0.0f), 800.0f);
    y2 = fminf(fmaxf(y2, 0.0f), 800.0f);
    bool valid = (x2 - x1 >= 1e-3f) && (y2 - y1 >= 1e-3f);
    float off = (float)l * 801.0f;
    recbox[s] = make_float4(x1, y1, x2, y2);
    recbn[s] = make_float4(x1 + off, y1 + off, x2 + off, y2 + off);
    unsigned int sk = valid ? dkey_of(lg) : 0xffffffffu;
    keys[s] = ((unsigned long long)sk << 31) |
              ((unsigned long long)(unsigned int)gidx << 13) |
              (unsigned long long)r;
}

// --------------- per-image bitonic sort (8192 in LDS) -----------------------
__global__ __launch_bounds__(1024) void k_sort(const unsigned long long* keys,
                                               const float4* recbox, const float4* recbn,
                                               const float* cl,
                                               float4* sbox, float4* sbn, float* slog,
                                               int* sinfo) {
    __shared__ unsigned long long s[8192];
    int n = blockIdx.x, tid = threadIdx.x;
    for (int e = tid; e < 8192; e += 1024)
        s[e] = (e < NSEL) ? keys[n * NSEL + e] : 0xffffffffffffffffull;
    __syncthreads();
    for (int k = 2; k <= 8192; k <<= 1) {
        for (int j = k >> 1; j > 0; j >>= 1) {
            for (int pp = tid; pp < 4096; pp += 1024) {
                int i = ((pp & ~(j - 1)) << 1) | (pp & (j - 1));
                int ix = i | j;
                bool up = ((i & k) == 0);
                unsigned long long A = s[i], B = s[ix];
                if ((A > B) == up) { s[i] = B; s[ix] = A; }
            }
            __syncthreads();
        }
    }
    for (int r = tid; r < PAD; r += 1024) {
        if (r < NSEL) {
            unsigned long long key = s[r];
            int pos = (int)(key & 0x1fffull);
            int src = n * NSEL + pos;
            sbox[n * PAD + r] = recbox[src];
            sbn[n * PAD + r] = recbn[src];
            slog[n * PAD + r] = cl[src];
            bool valid = ((unsigned int)(key >> 31) != 0xffffffffu);
            int lvl = (pos >= 4000) ? 4 : (pos >= 3000) ? 3 : (pos >= 2000) ? 2
                      : (pos >= 1000) ? 1 : 0;
            sinfo[n * PAD + r] = valid ? lvl : -1;
        } else {
            sbox[n * PAD + r] = make_float4(0.f, 0.f, 0.f, 0.f);
            sbn[n * PAD + r] = make_float4(0.f, 0.f, 0.f, 0.f);
            slog[n * PAD + r] = 0.f;
            sinfo[n * PAD + r] = -1;
        }
    }
}

// --------------- compact per-(image,level) valid boxes to global ------------
// Output: cbox[(n*NLV+l)*1024 + i] (zero-padded), clrank (sorted rank), ccnt.
__global__ __launch_bounds__(1024) void k_compact(const float4* sbn, const int* sinfo,
                                                  float4* cbox, short* clrank, int* ccnt) {
    int l = blockIdx.x, n = blockIdx.y;
    int tid = threadIdx.x, w = tid >> 6, lane = tid & 63;
    __shared__ int wsum[16];
    int base = tid * 5;                      // 5*1024 = 5120 >= PAD
    bool hit[5];
    int c = 0;
    #pragma unroll
    for (int k = 0; k < 5; ++k) {
        int r = base + k;
        hit[k] = (r < PAD) && (sinfo[n * PAD + r] == l);
        c += hit[k] ? 1 : 0;
    }
    int v = c;
    #pragma unroll
    for (int d2 = 1; d2 < 64; d2 <<= 1) {
        int t2 = __shfl_up(v, d2, 64);
        if (lane >= d2) v += t2;
    }
    if (lane == 63) wsum[w] = v;
    __syncthreads();
    int woff = 0, cnt = 0;
    #pragma unroll
    for (int ww = 0; ww < 16; ++ww) {
        int s2 = wsum[ww];
        if (ww < w) woff += s2;
        cnt += s2;
    }
    int obase = (n * NLV + l) * 1024;
    int pos = woff + v - c;                  // exclusive prefix
    #pragma unroll
    for (int k = 0; k < 5; ++k) {
        if (hit[k]) {
            cbox[obase + pos] = sbn[n * PAD + (base + k)];
            clrank[obase + pos] = (short)(base + k);
            ++pos;
        }
    }
    for (int i = cnt + tid; i < 1024; i += 1024) {   // zero-pad dummies
        cbox[obase + i] = make_float4(0.f, 0.f, 0.f, 0.f);
        clrank[obase + i] = 0;
    }
    if (tid == 0) ccnt[n * NLV + l] = cnt;
}

// --------------- pairwise suppression mask, whole-chip parallel -------------
// MT is TRANSPOSED: MT[(nl*16 + colword)*1024 + row] = 64-bit suppression
// word of `row` over boxes colword*64+lane. Upper triangle (cj>=ci) only.
__global__ __launch_bounds__(256) void k_mask(const float4* cbox, const int* ccnt,
                                              unsigned long long* MT) {
#pragma clang fp contract(off)
    int n = blockIdx.z, l = blockIdx.y;
    int ci = blockIdx.x >> 4, cj = blockIdx.x & 15;
    int nl = n * NLV + l;
    int cnt = ccnt[nl];
    int nw = (cnt + 63) / 64;
    if (cj < ci || cj >= nw) return;
    __shared__ float4 bi[64], bj[64];
    int tid = threadIdx.x;
    if (tid < 64) bj[tid] = cbox[nl * 1024 + cj * 64 + tid];
    else if (tid < 128) bi[tid - 64] = cbox[nl * 1024 + ci * 64 + (tid - 64)];
    __syncthreads();
    int w = tid >> 6, lane = tid & 63;
    float4 B = bj[lane];
    float a2 = (B.z - B.x) * (B.w - B.y);
    unsigned long long* outp = MT + ((size_t)nl * 16 + cj) * 1024 + ci * 64;
    #pragma unroll
    for (int t = 0; t < 16; ++t) {
        int i = w * 16 + t;
        float4 A = bi[i];
        float a1 = (A.z - A.x) * (A.w - A.y);
        float ltx = fmaxf(A.x, B.x), lty = fmaxf(A.y, B.y);
        float rbx = fminf(A.z, B.z), rby = fminf(A.w, B.w);
        float wx = fmaxf(rbx - ltx, 0.f), wy = fmaxf(rby - lty, 0.f);
        float inter = wx * wy;
        float iou = inter / ((a1 + a2) - inter);   // NaN (0/0) -> false, like jnp
        unsigned long long word = __ballot(iou > 0.7f);
        if (lane == 0) outp[i] = word;
    }
}

// --------------- serial greedy scan: bit ops only ---------------------------
// Diag rows preloaded per-wave (registers); resolve via readlane chain;
// push = 1 coalesced u64 load + keep-bit select + 6-step shfl-OR reduce.
// NOTE: __builtin_amdgcn_readlane returns SIGNED int — cast through
// (unsigned int) before widening to u64 (round-4 bug).
__global__ __launch_bounds__(1024) void k_scan(const unsigned long long* MT,
                                               const int* ccnt, const short* clrank,
                                               unsigned long long* keepmask) {
    int l = blockIdx.x, n = blockIdx.y;
    int nl = n * NLV + l;
    int tid = threadIdx.x, w = tid >> 6, lane = tid & 63;
    __shared__ unsigned long long Rw[16];
    __shared__ unsigned long long keepw[16];
    int cnt = ccnt[nl];
    int nw = (cnt + 63) / 64;
    if (tid < 16) { Rw[tid] = 0; keepw[tid] = 0; }

    // preload this wave's diagonal rows (1 u64/lane, coalesced)
    unsigned int dlo = 0, dhi = 0;
    if (w < nw) {
        unsigned long long Dreg = MT[((size_t)nl * 16 + w) * 1024 + w * 64 + lane];
        dlo = (unsigned int)Dreg;
        dhi = (unsigned int)(Dreg >> 32);
    }
    __syncthreads();

    for (int cc = 0; cc < nw; ++cc) {
        if (w == cc) {   // register resolve by wave cc
            int nb = min(64, cnt - cc * 64);
            unsigned long long Rc = Rw[cc];
            unsigned long long pend = ((nb == 64) ? ~0ull : ((1ull << nb) - 1ull)) & ~Rc;
            unsigned long long K = 0;
            while (pend) {
                int b = __builtin_amdgcn_readfirstlane(
                            (int)(__ffsll((long long)pend) - 1));
                K |= 1ull << b;
                unsigned long long row =
                    ((unsigned long long)(unsigned int)__builtin_amdgcn_readlane(dhi, b) << 32) |
                    (unsigned long long)(unsigned int)__builtin_amdgcn_readlane(dlo, b);
                Rc |= row;                   // self-bit set (iou=1): clears b from pend
                pend &= ~Rc;
            }
            if (lane == 0) keepw[cc] = K;
        }
        __syncthreads();
        int jw = cc + 1 + w;                 // push: one later word per wave
        if (jw < nw) {
            unsigned long long K = keepw[cc];
            if (K) {
                unsigned long long row = MT[((size_t)nl * 16 + jw) * 1024 + cc * 64 + lane];
                unsigned int vlo = 0, vhi = 0;
                if ((K >> lane) & 1ull) { vlo = (unsigned int)row; vhi = (unsigned int)(row >> 32); }
                #pragma unroll
                for (int m = 1; m < 64; m <<= 1) {
                    vlo |= (unsigned int)__shfl_xor((int)vlo, m, 64);
                    vhi |= (unsigned int)__shfl_xor((int)vhi, m, 64);
                }
                if (lane == 0)
                    Rw[jw] |= ((unsigned long long)vhi << 32) | (unsigned long long)vlo;
            }
        }
        __syncthreads();
    }
    // emit keep bits back to global sorted positions
    for (int m = tid; m < nw * 64; m += 1024) {
        int cc = m >> 6, b = m & 63;
        if ((keepw[cc] >> b) & 1ull) {
            int r = (int)clrank[nl * 1024 + m];
            atomicOr(&keepmask[n * CH + (r >> 6)], 1ull << (r & 63));
        }
    }
}

// --------------- zero-init + emit first 1000 kept (score order) -------------
__global__ __launch_bounds__(256) void k_epi(const unsigned long long* keepmask,
                                             const float4* sbox, const float* slog,
                                             float* out) {
    int n = blockIdx.x, tid = threadIdx.x;
    __shared__ unsigned long long kw[CH];
    __shared__ int pref[CH];
    // zero-init this image's output slice (replaces hipMemsetAsync)
    for (int i = tid; i < POSTN; i += 256) {
        ((float4*)out)[n * POSTN + i] = make_float4(0.f, 0.f, 0.f, 0.f);
        out[NIMG * POSTN * 4 + n * POSTN + i] = 0.f;
    }
    if (tid < CH) kw[tid] = keepmask[n * CH + tid];
    __syncthreads();
    if (tid == 0) {
        int run = 0;
        for (int w2 = 0; w2 < CH; ++w2) { pref[w2] = run; run += __popcll(kw[w2]); }
    }
    __syncthreads();
    for (int i = tid; i < NSEL; i += 256) {
        int q = i >> 6, b = i & 63;
        if ((kw[q] >> b) & 1ull) {
            int rank = pref[q] + __popcll(kw[q] & ((1ull << b) - 1ull));
            if (rank < POSTN) {
                float4 bx = sbox[n * PAD + i];
                float lg = slog[n * PAD + i];
                ((float4*)out)[n * POSTN + rank] = bx;
                out[NIMG * POSTN * 4 + n * POSTN + rank] = 1.0f / (1.0f + expf(-lg));
            }
        }
    }
}

extern "C" void kernel_launch(void* const* d_in, const int* in_sizes, int n_in,
                              void* d_out, int out_size, void* d_ws, size_t ws_size,
                              hipStream_t stream) {
    Ptrs P;
    bool interleaved = (in_sizes[1] == 4 * in_sizes[0]);  // obj0,delta0,obj1,... vs obj0..4,delta0..4
    for (int i = 0; i < NLV; ++i) {
        if (interleaved) {
            P.obj[i] = (const float*)d_in[2 * i];
            P.del[i] = (const float*)d_in[2 * i + 1];
        } else {
            P.obj[i] = (const float*)d_in[i];
            P.del[i] = (const float*)d_in[NLV + i];
        }
    }
    P.anch = (const float*)d_in[10];

    char* w = (char*)d_ws;
    size_t off = 0;
    auto alloc = [&](size_t bytes) {
        void* p = w + off;
        off = (off + bytes + 255) & ~(size_t)255;
        return p;
    };
    unsigned long long* keepmask = (unsigned long long*)alloc((size_t)NIMG * CH * 8);
    int* cg      = (int*)alloc((size_t)TSEL * 4);
    float* cl    = (float*)alloc((size_t)TSEL * 4);
    unsigned long long* keys = (unsigned long long*)alloc((size_t)TSEL * 8);
    float4* recbox = (float4*)alloc((size_t)TSEL * 16);
    float4* recbn  = (float4*)alloc((size_t)TSEL * 16);
    float4* sbox = (float4*)alloc((size_t)NIMG * PAD * 16);
    float4* sbn  = (float4*)alloc((size_t)NIMG * PAD * 16);
    float* slog  = (float*)alloc((size_t)NIMG * PAD * 4);
    int* sinfo   = (int*)alloc((size_t)NIMG * PAD * 4);
    float4* cbox = (float4*)alloc((size_t)NIMG * NLV * 1024 * 16);
    short* clrank = (short*)alloc((size_t)NIMG * NLV * 1024 * 2);
    int* ccnt    = (int*)alloc((size_t)NIMG * NLV * 4);
    unsigned long long* MT = (unsigned long long*)alloc((size_t)NIMG * NLV * 16 * 1024 * 8);
    (void)ws_size; (void)n_in;

    k_select<<<NIMG * NLV, 1024, 0, stream>>>(P, cg, cl);
    k_build<<<(TSEL + 255) / 256, 256, 0, stream>>>(P, cg, cl, keys, recbox, recbn, keepmask);
    k_sort<<<NIMG, 1024, 0, stream>>>(keys, recbox, recbn, cl, sbox, sbn, slog, sinfo);
    k_compact<<<dim3(NLV, NIMG), 1024, 0, stream>>>(sbn, sinfo, cbox, clrank, ccnt);
    k_mask<<<dim3(256, NLV, NIMG), 256, 0, stream>>>(cbox, ccnt, MT);
    k_scan<<<dim3(NLV, NIMG), 1024, 0, stream>>>(MT, ccnt, clrank, keepmask);
    k_epi<<<NIMG, 256, 0, stream>>>(keepmask, sbox, slog, (float*)d_out);
}